// Round 5
// baseline (488.682 us; speedup 1.0000x reference)
//
#include <hip/hip_runtime.h>
#include <math.h>

// B=4, S=2048, F=8, D=256, H=8, L=2, FF=1024, NSK=2000
#define SEQ   2048
#define BATCH 4
#define NTOK  8192
#define DM    256
#define NHD   8
#define DHD   32
#define DFF   1024
#define NSKC  2000

typedef __attribute__((ext_vector_type(8))) short short8;
typedef __attribute__((ext_vector_type(4))) float f32x4;
typedef unsigned short ushort_t;

// 1/sqrt(32) * log2(e): folded into Q so scores come out in exp2 domain.
#define QPRE ((float)(0.17677669529663687 * 1.4426950408889634))

__device__ __forceinline__ ushort_t f2bf(float x) {
    union { float f; unsigned u; } c; c.f = x;
    unsigned r = c.u + 0x7FFFu + ((c.u >> 16) & 1u);
    return (ushort_t)(r >> 16);
}

// ---------------------------------------------------------------------------
// Weight conversion via LDS-tiled 32x32 transpose: dst[n][k] = bf16(src[k][n])
// coalesced reads (n fast) and coalesced writes (k fast). Zero-pad n >= N.
// ---------------------------------------------------------------------------
struct ConvSeg { const float* src; ushort_t* dst; int K; int N; int Npad; };
struct ConvArgs { ConvSeg s[14]; };

__global__ __launch_bounds__(256) void convert_kernel(ConvArgs args) {
    ConvSeg sg = args.s[blockIdx.z];
    int n0 = blockIdx.x * 32, k0 = blockIdx.y * 32;
    if (n0 >= sg.Npad || k0 >= sg.K) return;
    __shared__ float T[32][33];
    int tid = threadIdx.x;
    int tn = tid & 31, tk4 = tid >> 5;
#pragma unroll
    for (int i = 0; i < 4; i++) {
        int kl = tk4 + i * 8;
        float v = 0.0f;
        if (n0 + tn < sg.N) v = sg.src[(size_t)(k0 + kl) * sg.N + n0 + tn];
        T[kl][tn] = v;
    }
    __syncthreads();
    int tk = tid & 31, tn4 = tid >> 5;
#pragma unroll
    for (int i = 0; i < 4; i++) {
        int nl = tn4 + i * 8;
        sg.dst[(size_t)(n0 + nl) * sg.K + k0 + tk] = f2bf(T[tk][nl]);
    }
}

// ---------------------------------------------------------------------------
// concat row [inter_e(256) | pat_e(64) | feat_e(64)] -> bf16
// ---------------------------------------------------------------------------
__global__ __launch_bounds__(384) void concat_kernel(
    const int* __restrict__ interactions, const int* __restrict__ patterns,
    const float* __restrict__ ff, const float* __restrict__ inter_emb,
    const float* __restrict__ pattern_emb, const float* __restrict__ feat_W,
    const float* __restrict__ feat_b, ushort_t* __restrict__ out)
{
    int tok = blockIdx.x;
    int j = threadIdx.x;
    float v;
    if (j < 256) {
        v = inter_emb[(size_t)interactions[tok] * 256 + j];
    } else if (j < 320) {
        v = pattern_emb[patterns[tok] * 64 + (j - 256)];
    } else {
        int c = j - 320;
        float acc = feat_b[c];
#pragma unroll
        for (int f = 0; f < 8; f++) acc += ff[tok * 8 + f] * feat_W[f * 64 + c];
        v = acc;
    }
    out[(size_t)tok * 384 + j] = f2bf(v);
}

// ---------------------------------------------------------------------------
// x += tanh(el*time_W+time_b) + pos*pos_W+pos_b ; write fp32 + bf16 copies
// ---------------------------------------------------------------------------
__global__ __launch_bounds__(256) void addenc_kernel(
    float* __restrict__ x, ushort_t* __restrict__ xb, const float* __restrict__ ff,
    const float* __restrict__ time_W, const float* __restrict__ time_b,
    const float* __restrict__ pos_W, const float* __restrict__ pos_b)
{
    int tok = blockIdx.x;
    int d = threadIdx.x;
    int s = tok & (SEQ - 1);
    float el = ff[tok * 8];
    float te = tanhf(el * time_W[d] + time_b[d]);
    float pe = ((float)s * (1.0f / (float)SEQ)) * pos_W[d] + pos_b[d];
    size_t idx = (size_t)tok * DM + d;
    float nv = x[idx] + te + pe;
    x[idx] = nv;
    xb[idx] = f2bf(nv);
}

// ---------------------------------------------------------------------------
// LayerNorm(x + r) in place; also writes bf16 copy.
// ---------------------------------------------------------------------------
__global__ __launch_bounds__(256) void ln_kernel(
    float* __restrict__ x, const float* __restrict__ r,
    const float* __restrict__ g, const float* __restrict__ b,
    ushort_t* __restrict__ xb)
{
    int tok = blockIdx.x;
    int d = threadIdx.x;
    size_t idx = (size_t)tok * DM + d;
    float v = x[idx] + r[idx];
    float s1 = v, s2 = v * v;
#pragma unroll
    for (int off = 32; off > 0; off >>= 1) {
        s1 += __shfl_down(s1, off, 64);
        s2 += __shfl_down(s2, off, 64);
    }
    __shared__ float red1[4], red2[4];
    int wid = d >> 6, lane = d & 63;
    if (lane == 0) { red1[wid] = s1; red2[wid] = s2; }
    __syncthreads();
    s1 = red1[0] + red1[1] + red1[2] + red1[3];
    s2 = red2[0] + red2[1] + red2[2] + red2[3];
    float mean = s1 * (1.0f / 256.0f);
    float var = s2 * (1.0f / 256.0f) - mean * mean;
    float inv = rsqrtf(var + 1e-6f);
    float nv = g[d] * (v - mean) * inv + b[d];
    x[idx] = nv;
    xb[idx] = f2bf(nv);
}

// ---------------------------------------------------------------------------
// bf16 MFMA GEMM: BM=128, BN=64, BK=32; 4 waves, each 32x64, 8 mfma/iter.
// Register prefetch of next K-tile. mode 0: fp32 out + bias.
// ---------------------------------------------------------------------------
__global__ __launch_bounds__(256) void gemm_bf16(
    const ushort_t* __restrict__ A, const ushort_t* __restrict__ Bt,
    int M, int N, int K,
    float* __restrict__ Cf, const float* __restrict__ b0)
{
    __shared__ ushort_t As[128][40];
    __shared__ ushort_t Bs[64][40];
    int m0 = blockIdx.y * 128, n0 = blockIdx.x * 64;
    int tid = threadIdx.x;
    int wv = tid >> 6, lane = tid & 63;
    int quad = lane >> 4, l16 = lane & 15;
    int srow = tid >> 2, sc = (tid & 3) << 3;

    f32x4 acc[2][4];
#pragma unroll
    for (int i = 0; i < 2; i++)
#pragma unroll
        for (int j = 0; j < 4; j++) acc[i][j] = (f32x4){0.f, 0.f, 0.f, 0.f};

    uint4 pa0 = *(const uint4*)&A[(size_t)(m0 + srow) * K + sc];
    uint4 pa1 = *(const uint4*)&A[(size_t)(m0 + 64 + srow) * K + sc];
    uint4 pbb = *(const uint4*)&Bt[(size_t)(n0 + srow) * K + sc];

    int msub = wv * 32;
    for (int k0 = 0; k0 < K; k0 += 32) {
        __syncthreads();
        *(uint4*)&As[srow][sc] = pa0;
        *(uint4*)&As[64 + srow][sc] = pa1;
        *(uint4*)&Bs[srow][sc] = pbb;
        __syncthreads();
        if (k0 + 32 < K) {
            pa0 = *(const uint4*)&A[(size_t)(m0 + srow) * K + k0 + 32 + sc];
            pa1 = *(const uint4*)&A[(size_t)(m0 + 64 + srow) * K + k0 + 32 + sc];
            pbb = *(const uint4*)&Bt[(size_t)(n0 + srow) * K + k0 + 32 + sc];
        }
        short8 af0 = *(const short8*)&As[msub + l16][quad * 8];
        short8 af1 = *(const short8*)&As[msub + 16 + l16][quad * 8];
        short8 bf0 = *(const short8*)&Bs[l16][quad * 8];
        short8 bf1 = *(const short8*)&Bs[16 + l16][quad * 8];
        short8 bf2 = *(const short8*)&Bs[32 + l16][quad * 8];
        short8 bf3 = *(const short8*)&Bs[48 + l16][quad * 8];
        acc[0][0] = __builtin_amdgcn_mfma_f32_16x16x32_bf16(af0, bf0, acc[0][0], 0, 0, 0);
        acc[0][1] = __builtin_amdgcn_mfma_f32_16x16x32_bf16(af0, bf1, acc[0][1], 0, 0, 0);
        acc[0][2] = __builtin_amdgcn_mfma_f32_16x16x32_bf16(af0, bf2, acc[0][2], 0, 0, 0);
        acc[0][3] = __builtin_amdgcn_mfma_f32_16x16x32_bf16(af0, bf3, acc[0][3], 0, 0, 0);
        acc[1][0] = __builtin_amdgcn_mfma_f32_16x16x32_bf16(af1, bf0, acc[1][0], 0, 0, 0);
        acc[1][1] = __builtin_amdgcn_mfma_f32_16x16x32_bf16(af1, bf1, acc[1][1], 0, 0, 0);
        acc[1][2] = __builtin_amdgcn_mfma_f32_16x16x32_bf16(af1, bf2, acc[1][2], 0, 0, 0);
        acc[1][3] = __builtin_amdgcn_mfma_f32_16x16x32_bf16(af1, bf3, acc[1][3], 0, 0, 0);
    }

#pragma unroll
    for (int mt = 0; mt < 2; mt++) {
#pragma unroll
        for (int nt = 0; nt < 4; nt++) {
            int n = n0 + nt * 16 + l16;
#pragma unroll
            for (int r = 0; r < 4; r++) {
                int m = m0 + msub + mt * 16 + quad * 4 + r;
                Cf[(size_t)m * N + n] = acc[mt][nt][r] + b0[n];
            }
        }
    }
}

// ---------------------------------------------------------------------------
// bf16 MFMA GEMM, BM=128 BN=128 BK=32: 4 waves, each 64x64, 16 mfma/iter.
// mode 1: gelu -> bf16 out
// mode 2: QKV epilogue: q (pre-scaled by QPRE), k -> (B,H,S,DH) bf16;
//         v -> V^T (B,H,DH,S) bf16 with column interleave s' so that the
//         attn B-fragment k-slot order matches the packed-P A-fragment.
// mode 3: fp32 + bias, col guard n < Nreal
// ---------------------------------------------------------------------------
__global__ __launch_bounds__(256) void gemm_bf16_128(
    const ushort_t* __restrict__ A, const ushort_t* __restrict__ Bt,
    int M, int N, int K, int mode,
    float* __restrict__ Cf, ushort_t* __restrict__ Cb,
    ushort_t* __restrict__ Ck, ushort_t* __restrict__ Cv,
    const float* __restrict__ b0, const float* __restrict__ b1,
    const float* __restrict__ b2, int Nreal)
{
    __shared__ ushort_t As[128][40];
    __shared__ ushort_t Bs[128][40];
    int m0 = blockIdx.y * 128, n0 = blockIdx.x * 128;
    int tid = threadIdx.x;
    int wv = tid >> 6, lane = tid & 63;
    int quad = lane >> 4, l16 = lane & 15;
    int wm = (wv >> 1) * 64, wn = (wv & 1) * 64;
    int srow = tid >> 1, sc = (tid & 1) << 4;

    f32x4 acc[4][4];
#pragma unroll
    for (int i = 0; i < 4; i++)
#pragma unroll
        for (int j = 0; j < 4; j++) acc[i][j] = (f32x4){0.f, 0.f, 0.f, 0.f};

    uint4 pa0 = *(const uint4*)&A[(size_t)(m0 + srow) * K + sc];
    uint4 pa1 = *(const uint4*)&A[(size_t)(m0 + srow) * K + sc + 8];
    uint4 pb0 = *(const uint4*)&Bt[(size_t)(n0 + srow) * K + sc];
    uint4 pb1 = *(const uint4*)&Bt[(size_t)(n0 + srow) * K + sc + 8];

    for (int k0 = 0; k0 < K; k0 += 32) {
        __syncthreads();
        *(uint4*)&As[srow][sc] = pa0;
        *(uint4*)&As[srow][sc + 8] = pa1;
        *(uint4*)&Bs[srow][sc] = pb0;
        *(uint4*)&Bs[srow][sc + 8] = pb1;
        __syncthreads();
        if (k0 + 32 < K) {
            pa0 = *(const uint4*)&A[(size_t)(m0 + srow) * K + k0 + 32 + sc];
            pa1 = *(const uint4*)&A[(size_t)(m0 + srow) * K + k0 + 32 + sc + 8];
            pb0 = *(const uint4*)&Bt[(size_t)(n0 + srow) * K + k0 + 32 + sc];
            pb1 = *(const uint4*)&Bt[(size_t)(n0 + srow) * K + k0 + 32 + sc + 8];
        }
        short8 af[4], bf[4];
#pragma unroll
        for (int i = 0; i < 4; i++) {
            af[i] = *(const short8*)&As[wm + i * 16 + l16][quad * 8];
            bf[i] = *(const short8*)&Bs[wn + i * 16 + l16][quad * 8];
        }
#pragma unroll
        for (int i = 0; i < 4; i++)
#pragma unroll
            for (int j = 0; j < 4; j++)
                acc[i][j] = __builtin_amdgcn_mfma_f32_16x16x32_bf16(af[i], bf[j], acc[i][j], 0, 0, 0);
    }

#pragma unroll
    for (int i = 0; i < 4; i++) {
#pragma unroll
        for (int j = 0; j < 4; j++) {
            int n = n0 + wn + j * 16 + l16;
#pragma unroll
            for (int r = 0; r < 4; r++) {
                int m = m0 + wm + i * 16 + quad * 4 + r;
                float v = acc[i][j][r];
                if (mode == 1) {
                    float t = v + b0[n];
                    t = 0.5f * t * (1.0f + erff(t * 0.70710678118654752f));
                    Cb[(size_t)m * N + n] = f2bf(t);
                } else if (mode == 3) {
                    if (n < Nreal) Cf[(size_t)m * Nreal + n] = v + b0[n];
                } else {
                    int which = n >> 8, idx = n & 255;
                    int hh = idx >> 5, d = idx & 31;
                    int s = m & (SEQ - 1), b = m >> 11;
                    if (which == 0)
                        Cb[(((size_t)(b * NHD + hh)) * SEQ + s) * DHD + d] =
                            f2bf((v + b0[idx]) * QPRE);
                    else if (which == 1)
                        Ck[(((size_t)(b * NHD + hh)) * SEQ + s) * DHD + d] = f2bf(v + b1[idx]);
                    else {
                        int sp = (s & ~31) | (((s & 15) << 1) | ((s >> 4) & 1));
                        Cv[(((size_t)(b * NHD + hh)) * DHD + d) * SEQ + sp] = f2bf(v + b2[idx]);
                    }
                }
            }
        }
    }
}

// ---------------------------------------------------------------------------
// MFMA flash attention, paired-tile waves; packed-P LDS (bf16x2 per b32,
// 4 ds_write_b32 per tile instead of 16 ds_write_b16); arithmetic kerple bias
// e = exp2(s - p*log2(1 + a*dist)) with 1/sqrt(32)*log2e pre-folded into Q.
// V^T is stored column-interleaved (s' = pair order) so the b128 V fragment's
// k-slot order matches the packed-P A fragment. No block-wide LDS or syncs.
// ---------------------------------------------------------------------------
__global__ __launch_bounds__(256) void attn_mfma(
    const ushort_t* __restrict__ qb, const ushort_t* __restrict__ kb,
    const ushort_t* __restrict__ vtb, const float* __restrict__ kp,
    const float* __restrict__ ka, ushort_t* __restrict__ ob)
{
    int h = blockIdx.y, b = blockIdx.z;
    int tid = threadIdx.x, wv = tid >> 6, lane = tid & 63;
    int quad = lane >> 4, l16 = lane & 15;
    __shared__ ushort_t P2[4][2][16 * 40];   // per-wave, per-tile: 16 rows x 20 b32

    float p = log1pf(__expf(kp[h]));     // softplus
    float a = log1pf(__expf(ka[h]));

    int bh = b * NHD + h;
    const ushort_t* Qh = qb + (size_t)bh * SEQ * DHD;
    const ushort_t* Kh = kb + (size_t)bh * SEQ * DHD;
    const ushort_t* Vh = vtb + (size_t)bh * DHD * SEQ;

    int j = blockIdx.x * 4 + wv;         // 0..63
    int tlo = j, thi = 127 - j;
    int qlo0 = tlo * 16, qhi0 = thi * 16;

    short8 qfl = *(const short8*)&Qh[(qlo0 + l16) * DHD + quad * 8];
    short8 qfh = *(const short8*)&Qh[(qhi0 + l16) * DHD + quad * 8];
    f32x4 ol0 = (f32x4){0.f,0.f,0.f,0.f}, ol1 = (f32x4){0.f,0.f,0.f,0.f};
    f32x4 oh0 = (f32x4){0.f,0.f,0.f,0.f}, oh1 = (f32x4){0.f,0.f,0.f,0.f};
    float lsl[4] = {0.f,0.f,0.f,0.f}, lsh[4] = {0.f,0.f,0.f,0.f};
    ushort_t* Pl = &P2[wv][0][0];
    ushort_t* Ph = &P2[wv][1][0];

    int nch_hi = (thi + 2) >> 1;
    int nch_lo = (tlo + 2) >> 1;
    int qsrh = qhi0 + quad * 4;
    int qsrl = qlo0 + quad * 4;

    for (int ch = 0; ch < nch_hi; ch++) {
        int k0 = ch * 32;
        short8 kf0 = *(const short8*)&Kh[(k0 + l16) * DHD + quad * 8];
        short8 kf1 = *(const short8*)&Kh[(k0 + 16 + l16) * DHD + quad * 8];
        short8 vf0 = *(const short8*)&Vh[l16 * SEQ + k0 + quad * 8];
        short8 vf1 = *(const short8*)&Vh[(16 + l16) * SEQ + k0 + quad * 8];
        f32x4 z = (f32x4){0.f,0.f,0.f,0.f};

        // ---- hi tile ----
        f32x4 s0 = __builtin_amdgcn_mfma_f32_16x16x32_bf16(qfh, kf0, z, 0, 0, 0);
        f32x4 s1 = __builtin_amdgcn_mfma_f32_16x16x32_bf16(qfh, kf1, z, 0, 0, 0);
        {
            float df = (float)(qsrh - k0 - l16);
            bool interior = (k0 + 31 <= qhi0);
#pragma unroll
            for (int r = 0; r < 4; r++) {
                float d0 = df + (float)r, d1 = d0 - 16.0f;
                float e0 = exp2f(s0[r] - p * __log2f(fmaf(a, d0, 1.0f)));
                float e1 = exp2f(s1[r] - p * __log2f(fmaf(a, d1, 1.0f)));
                if (!interior) {
                    e0 = (d0 >= 0.0f) ? e0 : 0.0f;
                    e1 = (d1 >= 0.0f) ? e1 : 0.0f;
                }
                lsh[r] += e0 + e1;
                unsigned pk = (unsigned)f2bf(e0) | ((unsigned)f2bf(e1) << 16);
                *(unsigned*)&Ph[(quad * 4 + r) * 40 + l16 * 2] = pk;
            }
        }

        // ---- lo tile (shares K/V frags) ----
        bool do_lo = (ch < nch_lo);
        if (do_lo) {
            f32x4 t0 = __builtin_amdgcn_mfma_f32_16x16x32_bf16(qfl, kf0, z, 0, 0, 0);
            f32x4 t1 = __builtin_amdgcn_mfma_f32_16x16x32_bf16(qfl, kf1, z, 0, 0, 0);
            float df = (float)(qsrl - k0 - l16);
            bool interior = (k0 + 31 <= qlo0);
#pragma unroll
            for (int r = 0; r < 4; r++) {
                float d0 = df + (float)r, d1 = d0 - 16.0f;
                float e0 = exp2f(t0[r] - p * __log2f(fmaf(a, d0, 1.0f)));
                float e1 = exp2f(t1[r] - p * __log2f(fmaf(a, d1, 1.0f)));
                if (!interior) {
                    e0 = (d0 >= 0.0f) ? e0 : 0.0f;
                    e1 = (d1 >= 0.0f) ? e1 : 0.0f;
                }
                lsl[r] += e0 + e1;
                unsigned pk = (unsigned)f2bf(e0) | ((unsigned)f2bf(e1) << 16);
                *(unsigned*)&Pl[(quad * 4 + r) * 40 + l16 * 2] = pk;
            }
        }

        __builtin_amdgcn_s_waitcnt(0xC07F);     // lgkmcnt(0): P writes visible
        __builtin_amdgcn_wave_barrier();        // pin write->read order
        short8 pfh = *(const short8*)&Ph[l16 * 40 + quad * 8];
        oh0 = __builtin_amdgcn_mfma_f32_16x16x32_bf16(pfh, vf0, oh0, 0, 0, 0);
        oh1 = __builtin_amdgcn_mfma_f32_16x16x32_bf16(pfh, vf1, oh1, 0, 0, 0);
        if (do_lo) {
            short8 pfl = *(const short8*)&Pl[l16 * 40 + quad * 8];
            ol0 = __builtin_amdgcn_mfma_f32_16x16x32_bf16(pfl, vf0, ol0, 0, 0, 0);
            ol1 = __builtin_amdgcn_mfma_f32_16x16x32_bf16(pfl, vf1, ol1, 0, 0, 0);
        }
    }

#pragma unroll
    for (int r = 0; r < 4; r++) {
#pragma unroll
        for (int off = 1; off < 16; off <<= 1) {
            lsh[r] += __shfl_xor(lsh[r], off, 16);
            lsl[r] += __shfl_xor(lsl[r], off, 16);
        }
    }
#pragma unroll
    for (int r = 0; r < 4; r++) {
        float rh = 1.0f / lsh[r];
        float rl = 1.0f / lsl[r];
        size_t bh_ = ((size_t)(b * SEQ + qsrh + r)) * DM + h * DHD;
        size_t bl_ = ((size_t)(b * SEQ + qsrl + r)) * DM + h * DHD;
        ob[bh_ + l16]      = f2bf(oh0[r] * rh);
        ob[bh_ + 16 + l16] = f2bf(oh1[r] * rh);
        ob[bl_ + l16]      = f2bf(ol0[r] * rl);
        ob[bl_ + 16 + l16] = f2bf(ol1[r] * rl);
    }
}

// ---------------------------------------------------------------------------
extern "C" void kernel_launch(void* const* d_in, const int* in_sizes, int n_in,
                              void* d_out, int out_size, void* d_ws, size_t ws_size,
                              hipStream_t stream) {
    const int*   interactions = (const int*)d_in[0];
    const int*   patterns     = (const int*)d_in[1];
    const float* ff           = (const float*)d_in[2];
    const float* inter_emb    = (const float*)d_in[3];
    const float* pattern_emb  = (const float*)d_in[4];
    const float* feat_W       = (const float*)d_in[5];
    const float* feat_b       = (const float*)d_in[6];
    const float* in_W         = (const float*)d_in[7];
    const float* in_b         = (const float*)d_in[8];
    const float* time_W       = (const float*)d_in[9];
    const float* time_b       = (const float*)d_in[10];
    const float* pos_W        = (const float*)d_in[11];
    const float* pos_b        = (const float*)d_in[12];
    const float* Wq           = (const float*)d_in[13];
    const float* bq           = (const float*)d_in[14];
    const float* Wk           = (const float*)d_in[15];
    const float* bk           = (const float*)d_in[16];
    const float* Wv           = (const float*)d_in[17];
    const float* bv           = (const float*)d_in[18];
    const float* Wo           = (const float*)d_in[19];
    const float* bo           = (const float*)d_in[20];
    const float* kerple_p     = (const float*)d_in[21];
    const float* kerple_a     = (const float*)d_in[22];
    const float* ln1_g        = (const float*)d_in[23];
    const float* ln1_b        = (const float*)d_in[24];
    const float* ln2_g        = (const float*)d_in[25];
    const float* ln2_b        = (const float*)d_in[26];
    const float* ffn_W1       = (const float*)d_in[27];
    const float* ffn_b1       = (const float*)d_in[28];
    const float* ffn_W2       = (const float*)d_in[29];
    const float* ffn_b2       = (const float*)d_in[30];
    const float* out_W        = (const float*)d_in[31];
    const float* out_b        = (const float*)d_in[32];
    float* out = (float*)d_out;

    // ---- workspace layout (bytes) ----
    char* wsb = (char*)d_ws;
    const size_t MB = 1024 * 1024;
    float*    x    = (float*)(wsb + 0);          //  8 MB fp32 activations
    float*    tmp  = (float*)(wsb + 8  * MB);    //  8 MB fp32 residual branch
    ushort_t* xb   = (ushort_t*)(wsb + 16 * MB); //  4 MB bf16 copy of x
    ushort_t* qbuf = (ushort_t*)(wsb + 20 * MB); //  4 MB bf16 Q (B,H,S,DH), pre-scaled
    ushort_t* kbuf = (ushort_t*)(wsb + 24 * MB); //  4 MB bf16 K (B,H,S,DH)
    ushort_t* vtbf = (ushort_t*)(wsb + 28 * MB); //  4 MB bf16 V^T (B,H,DH,S) interleaved
    ushort_t* shrd = (ushort_t*)(wsb + 32 * MB); // 16 MB: cbuf / o_bf / h_bf
    ushort_t* cbuf = shrd;                        // 8192x384 bf16
    ushort_t* o_bf = shrd;                        // 8192x256 bf16
    ushort_t* h_bf = shrd;                        // 8192x1024 bf16
    char* wp = wsb + 48 * MB;
    ushort_t* inWt  = (ushort_t*)wp;  wp += 256  * 384 * 2;       // [256][384]
    ushort_t* qkvWt = (ushort_t*)wp;  wp += 2 * 768 * 256 * 2;    // [l][768][256]
    ushort_t* WoT   = (ushort_t*)wp;  wp += 2 * 256 * 256 * 2;    // [l][256][256]
    ushort_t* W1T   = (ushort_t*)wp;  wp += 2 * 1024 * 256 * 2;   // [l][1024][256]
    ushort_t* W2T   = (ushort_t*)wp;  wp += 2 * 256 * 1024 * 2;   // [l][256][1024]
    ushort_t* outWt = (ushort_t*)wp;  wp += 2048 * 256 * 2;       // [2048][256] zero-pad

    // ---- weight conversion (tiled transpose -> bf16) ----
    ConvArgs ca;
    int D2 = 256 * 256;
    ca.s[0]  = { in_W,              inWt,               384,  256,  256 };
    ca.s[1]  = { Wq,                qkvWt,              256,  256,  256 };
    ca.s[2]  = { Wk,                qkvWt + 1 * D2,     256,  256,  256 };
    ca.s[3]  = { Wv,                qkvWt + 2 * D2,     256,  256,  256 };
    ca.s[4]  = { Wq + D2,           qkvWt + 3 * D2,     256,  256,  256 };
    ca.s[5]  = { Wk + D2,           qkvWt + 4 * D2,     256,  256,  256 };
    ca.s[6]  = { Wv + D2,           qkvWt + 5 * D2,     256,  256,  256 };
    ca.s[7]  = { Wo,                WoT,                256,  256,  256 };
    ca.s[8]  = { Wo + D2,           WoT + D2,           256,  256,  256 };
    ca.s[9]  = { ffn_W1,            W1T,                256,  1024, 1024 };
    ca.s[10] = { ffn_W1 + 4 * D2,   W1T + 4 * D2,       256,  1024, 1024 };
    ca.s[11] = { ffn_W2,            W2T,                1024, 256,  256 };
    ca.s[12] = { ffn_W2 + 4 * D2,   W2T + 4 * D2,       1024, 256,  256 };
    ca.s[13] = { out_W,             outWt,              256,  2000, 2048 };
    convert_kernel<<<dim3(64, 32, 14), 256, 0, stream>>>(ca);

    // ---- input projection + encodings ----
    concat_kernel<<<NTOK, 384, 0, stream>>>(interactions, patterns, ff,
                                            inter_emb, pattern_emb, feat_W, feat_b, cbuf);
    gemm_bf16<<<dim3(4, 64), 256, 0, stream>>>(cbuf, inWt, NTOK, 256, 384, x, in_b);
    addenc_kernel<<<NTOK, 256, 0, stream>>>(x, xb, ff, time_W, time_b, pos_W, pos_b);

    for (int l = 0; l < 2; l++) {
        gemm_bf16_128<<<dim3(6, 64), 256, 0, stream>>>(
            xb, qkvWt + (size_t)l * 768 * 256, NTOK, 768, 256, 2,
            nullptr, qbuf, kbuf, vtbf,
            bq + l * 256, bk + l * 256, bv + l * 256, 0);
        attn_mfma<<<dim3(16, NHD, BATCH), 256, 0, stream>>>(
            qbuf, kbuf, vtbf, kerple_p + l * NHD, kerple_a + l * NHD, o_bf);
        gemm_bf16<<<dim3(4, 64), 256, 0, stream>>>(
            o_bf, WoT + (size_t)l * D2, NTOK, 256, 256, tmp, bo + l * 256);
        ln_kernel<<<NTOK, 256, 0, stream>>>(x, tmp, ln1_g + l * 256, ln1_b + l * 256, xb);
        gemm_bf16_128<<<dim3(8, 64), 256, 0, stream>>>(
            xb, W1T + (size_t)l * 4 * D2, NTOK, 1024, 256, 1,
            nullptr, h_bf, nullptr, nullptr, ffn_b1 + l * 1024, nullptr, nullptr, 0);
        gemm_bf16<<<dim3(4, 64), 256, 0, stream>>>(
            h_bf, W2T + (size_t)l * 4 * D2, NTOK, 256, 1024, tmp, ffn_b2 + l * 256);
        ln_kernel<<<NTOK, 256, 0, stream>>>(x, tmp, ln2_g + l * 256, ln2_b + l * 256, xb);
    }

    // ---- output projection (N=2048 padded, guard to 2000) ----
    gemm_bf16_128<<<dim3(16, 64), 256, 0, stream>>>(
        xb, outWt, NTOK, 2048, 256, 3,
        out, nullptr, nullptr, nullptr, out_b, nullptr, nullptr, NSKC);
}

// Round 6
// 483.113 us; speedup vs baseline: 1.0115x; 1.0115x over previous
//
#include <hip/hip_runtime.h>
#include <math.h>

// B=4, S=2048, F=8, D=256, H=8, L=2, FF=1024, NSK=2000
#define SEQ   2048
#define BATCH 4
#define NTOK  8192
#define DM    256
#define NHD   8
#define DHD   32
#define DFF   1024
#define NSKC  2000

typedef __attribute__((ext_vector_type(8))) short short8;
typedef __attribute__((ext_vector_type(4))) float f32x4;
typedef unsigned short ushort_t;

// 1/sqrt(32) * log2(e): folded into Q so scores come out in exp2 domain.
#define QPRE ((float)(0.17677669529663687 * 1.4426950408889634))

__device__ __forceinline__ ushort_t f2bf(float x) {
    union { float f; unsigned u; } c; c.f = x;
    unsigned r = c.u + 0x7FFFu + ((c.u >> 16) & 1u);
    return (ushort_t)(r >> 16);
}

#if __has_builtin(__builtin_amdgcn_cvt_pk_bf16_f32)
typedef __attribute__((ext_vector_type(2))) __bf16 bf16x2_t;
__device__ __forceinline__ unsigned pack_bf16(float a, float b) {
    bf16x2_t r = __builtin_amdgcn_cvt_pk_bf16_f32(a, b);
    union { bf16x2_t v; unsigned u; } c; c.v = r;
    return c.u;
}
#else
__device__ __forceinline__ unsigned pack_bf16(float a, float b) {
    return (unsigned)f2bf(a) | ((unsigned)f2bf(b) << 16);
}
#endif

__device__ __forceinline__ float bf2f(ushort_t x) {
    union { unsigned u; float f; } c; c.u = ((unsigned)x) << 16;
    return c.f;
}

// ---------------------------------------------------------------------------
// Weight conversion, exact tile grid: dst[n][k] = bf16(src[k][n]).
// ---------------------------------------------------------------------------
struct ConvSeg { const float* src; ushort_t* dst; int K; int N; int ntx; int base; };
struct ConvArgs { ConvSeg s[14]; };

__global__ __launch_bounds__(256) void convert_kernel(ConvArgs args) {
    int bid = blockIdx.x;
    int si = 0;
#pragma unroll
    for (int i = 1; i < 14; i++) if (bid >= args.s[i].base) si = i;
    ConvSeg sg = args.s[si];
    int local = bid - sg.base;
    int ty = local / sg.ntx;
    int tx = local - ty * sg.ntx;
    int n0 = tx * 32, k0 = ty * 32;
    __shared__ float T[32][33];
    int tid = threadIdx.x;
    int tn = tid & 31, tk4 = tid >> 5;
#pragma unroll
    for (int i = 0; i < 4; i++) {
        int kl = tk4 + i * 8;
        float v = 0.0f;
        if (n0 + tn < sg.N) v = sg.src[(size_t)(k0 + kl) * sg.N + n0 + tn];
        T[kl][tn] = v;
    }
    __syncthreads();
    int tk = tid & 31, tn4 = tid >> 5;
#pragma unroll
    for (int i = 0; i < 4; i++) {
        int nl = tn4 + i * 8;
        sg.dst[(size_t)(n0 + nl) * sg.K + k0 + tk] = f2bf(T[tk][nl]);
    }
}

// ---------------------------------------------------------------------------
// concat row [inter_e(256) | pat_e(64) | feat_e(64)] -> bf16
// ---------------------------------------------------------------------------
__global__ __launch_bounds__(384) void concat_kernel(
    const int* __restrict__ interactions, const int* __restrict__ patterns,
    const float* __restrict__ ff, const float* __restrict__ inter_emb,
    const float* __restrict__ pattern_emb, const float* __restrict__ feat_W,
    const float* __restrict__ feat_b, ushort_t* __restrict__ out)
{
    int tok = blockIdx.x;
    int j = threadIdx.x;
    float v;
    if (j < 256) {
        v = inter_emb[(size_t)interactions[tok] * 256 + j];
    } else if (j < 320) {
        v = pattern_emb[patterns[tok] * 64 + (j - 256)];
    } else {
        int c = j - 320;
        float acc = feat_b[c];
#pragma unroll
        for (int f = 0; f < 8; f++) acc += ff[tok * 8 + f] * feat_W[f * 64 + c];
        v = acc;
    }
    out[(size_t)tok * 384 + j] = f2bf(v);
}

// ---------------------------------------------------------------------------
// LayerNorm(x + r(bf16)) in place; also writes bf16 copy.
// ---------------------------------------------------------------------------
__global__ __launch_bounds__(256) void ln_kernel(
    float* __restrict__ x, const ushort_t* __restrict__ r,
    const float* __restrict__ g, const float* __restrict__ b,
    ushort_t* __restrict__ xb)
{
    int tok = blockIdx.x;
    int d = threadIdx.x;
    size_t idx = (size_t)tok * DM + d;
    float v = x[idx] + bf2f(r[idx]);
    float s1 = v, s2 = v * v;
#pragma unroll
    for (int off = 32; off > 0; off >>= 1) {
        s1 += __shfl_down(s1, off, 64);
        s2 += __shfl_down(s2, off, 64);
    }
    __shared__ float red1[4], red2[4];
    int wid = d >> 6, lane = d & 63;
    if (lane == 0) { red1[wid] = s1; red2[wid] = s2; }
    __syncthreads();
    s1 = red1[0] + red1[1] + red1[2] + red1[3];
    s2 = red2[0] + red2[1] + red2[2] + red2[3];
    float mean = s1 * (1.0f / 256.0f);
    float var = s2 * (1.0f / 256.0f) - mean * mean;
    float inv = rsqrtf(var + 1e-6f);
    float nv = g[d] * (v - mean) * inv + b[d];
    x[idx] = nv;
    xb[idx] = f2bf(nv);
}

// ---------------------------------------------------------------------------
// bf16 MFMA GEMM, BM=64 BN=64 BK=32: 4 waves, each 16x64, 4 mfma/iter.
// Grid 2x CU count for the N=256 shapes -> barrier overlap across blocks.
// mode 4: in-proj epilogue (bias + time/pos encodings) -> x fp32 + xb bf16
// mode 5: bf16 out + bias (residual branches)
// ---------------------------------------------------------------------------
__global__ __launch_bounds__(256) void gemm64(
    const ushort_t* __restrict__ A, const ushort_t* __restrict__ Bt,
    int M, int N, int K, int mode,
    float* __restrict__ Cf, ushort_t* __restrict__ Cb,
    const float* __restrict__ b0,
    const float* __restrict__ ffg, const float* __restrict__ tW,
    const float* __restrict__ tb, const float* __restrict__ pW,
    const float* __restrict__ pb)
{
    __shared__ ushort_t As[64][40];
    __shared__ ushort_t Bs[64][40];
    int m0 = blockIdx.y * 64, n0 = blockIdx.x * 64;
    int tid = threadIdx.x;
    int wv = tid >> 6, lane = tid & 63;
    int quad = lane >> 4, l16 = lane & 15;
    int srow = tid >> 2, sc = (tid & 3) << 3;

    f32x4 acc[4];
#pragma unroll
    for (int j = 0; j < 4; j++) acc[j] = (f32x4){0.f, 0.f, 0.f, 0.f};

    uint4 pa = *(const uint4*)&A[(size_t)(m0 + srow) * K + sc];
    uint4 pbv = *(const uint4*)&Bt[(size_t)(n0 + srow) * K + sc];

    int mrow = wv * 16;
    for (int k0 = 0; k0 < K; k0 += 32) {
        __syncthreads();
        *(uint4*)&As[srow][sc] = pa;
        *(uint4*)&Bs[srow][sc] = pbv;
        __syncthreads();
        if (k0 + 32 < K) {
            pa = *(const uint4*)&A[(size_t)(m0 + srow) * K + k0 + 32 + sc];
            pbv = *(const uint4*)&Bt[(size_t)(n0 + srow) * K + k0 + 32 + sc];
        }
        short8 af = *(const short8*)&As[mrow + l16][quad * 8];
        short8 bf0 = *(const short8*)&Bs[l16][quad * 8];
        short8 bf1 = *(const short8*)&Bs[16 + l16][quad * 8];
        short8 bf2 = *(const short8*)&Bs[32 + l16][quad * 8];
        short8 bf3 = *(const short8*)&Bs[48 + l16][quad * 8];
        acc[0] = __builtin_amdgcn_mfma_f32_16x16x32_bf16(af, bf0, acc[0], 0, 0, 0);
        acc[1] = __builtin_amdgcn_mfma_f32_16x16x32_bf16(af, bf1, acc[1], 0, 0, 0);
        acc[2] = __builtin_amdgcn_mfma_f32_16x16x32_bf16(af, bf2, acc[2], 0, 0, 0);
        acc[3] = __builtin_amdgcn_mfma_f32_16x16x32_bf16(af, bf3, acc[3], 0, 0, 0);
    }

#pragma unroll
    for (int r = 0; r < 4; r++) {
        int m = m0 + mrow + quad * 4 + r;
        if (mode == 4) {
            int s = m & (SEQ - 1);
            float el = ffg[m * 8];
            float pos = (float)s * (1.0f / (float)SEQ);
#pragma unroll
            for (int nt = 0; nt < 4; nt++) {
                int n = n0 + nt * 16 + l16;
                float te = tanhf(el * tW[n] + tb[n]);
                float pe = pos * pW[n] + pb[n];
                float nv = acc[nt][r] + b0[n] + te + pe;
                Cf[(size_t)m * N + n] = nv;
                Cb[(size_t)m * N + n] = f2bf(nv);
            }
        } else {
#pragma unroll
            for (int nt = 0; nt < 4; nt++) {
                int n = n0 + nt * 16 + l16;
                Cb[(size_t)m * N + n] = f2bf(acc[nt][r] + b0[n]);
            }
        }
    }
}

// ---------------------------------------------------------------------------
// bf16 MFMA GEMM, BM=128 BN=128 BK=32: 4 waves, each 64x64, 16 mfma/iter.
// mode 1: gelu -> bf16 out
// mode 2: QKV epilogue (q pre-scaled by QPRE, k -> (B,H,S,DH); v -> V^T
//         (B,H,DH,S) with pair-interleaved columns matching packed-P)
// mode 3: fp32 + bias, col guard n < Nreal
// ---------------------------------------------------------------------------
__global__ __launch_bounds__(256) void gemm_bf16_128(
    const ushort_t* __restrict__ A, const ushort_t* __restrict__ Bt,
    int M, int N, int K, int mode,
    float* __restrict__ Cf, ushort_t* __restrict__ Cb,
    ushort_t* __restrict__ Ck, ushort_t* __restrict__ Cv,
    const float* __restrict__ b0, const float* __restrict__ b1,
    const float* __restrict__ b2, int Nreal)
{
    __shared__ ushort_t As[128][40];
    __shared__ ushort_t Bs[128][40];
    int m0 = blockIdx.y * 128, n0 = blockIdx.x * 128;
    int tid = threadIdx.x;
    int wv = tid >> 6, lane = tid & 63;
    int quad = lane >> 4, l16 = lane & 15;
    int wm = (wv >> 1) * 64, wn = (wv & 1) * 64;
    int srow = tid >> 1, sc = (tid & 1) << 4;

    f32x4 acc[4][4];
#pragma unroll
    for (int i = 0; i < 4; i++)
#pragma unroll
        for (int j = 0; j < 4; j++) acc[i][j] = (f32x4){0.f, 0.f, 0.f, 0.f};

    uint4 pa0 = *(const uint4*)&A[(size_t)(m0 + srow) * K + sc];
    uint4 pa1 = *(const uint4*)&A[(size_t)(m0 + srow) * K + sc + 8];
    uint4 pb0 = *(const uint4*)&Bt[(size_t)(n0 + srow) * K + sc];
    uint4 pb1 = *(const uint4*)&Bt[(size_t)(n0 + srow) * K + sc + 8];

    for (int k0 = 0; k0 < K; k0 += 32) {
        __syncthreads();
        *(uint4*)&As[srow][sc] = pa0;
        *(uint4*)&As[srow][sc + 8] = pa1;
        *(uint4*)&Bs[srow][sc] = pb0;
        *(uint4*)&Bs[srow][sc + 8] = pb1;
        __syncthreads();
        if (k0 + 32 < K) {
            pa0 = *(const uint4*)&A[(size_t)(m0 + srow) * K + k0 + 32 + sc];
            pa1 = *(const uint4*)&A[(size_t)(m0 + srow) * K + k0 + 32 + sc + 8];
            pb0 = *(const uint4*)&Bt[(size_t)(n0 + srow) * K + k0 + 32 + sc];
            pb1 = *(const uint4*)&Bt[(size_t)(n0 + srow) * K + k0 + 32 + sc + 8];
        }
        short8 af[4], bf[4];
#pragma unroll
        for (int i = 0; i < 4; i++) {
            af[i] = *(const short8*)&As[wm + i * 16 + l16][quad * 8];
            bf[i] = *(const short8*)&Bs[wn + i * 16 + l16][quad * 8];
        }
#pragma unroll
        for (int i = 0; i < 4; i++)
#pragma unroll
            for (int j = 0; j < 4; j++)
                acc[i][j] = __builtin_amdgcn_mfma_f32_16x16x32_bf16(af[i], bf[j], acc[i][j], 0, 0, 0);
    }

#pragma unroll
    for (int i = 0; i < 4; i++) {
#pragma unroll
        for (int j = 0; j < 4; j++) {
            int n = n0 + wn + j * 16 + l16;
#pragma unroll
            for (int r = 0; r < 4; r++) {
                int m = m0 + wm + i * 16 + quad * 4 + r;
                float v = acc[i][j][r];
                if (mode == 1) {
                    float t = v + b0[n];
                    t = 0.5f * t * (1.0f + erff(t * 0.70710678118654752f));
                    Cb[(size_t)m * N + n] = f2bf(t);
                } else if (mode == 3) {
                    if (n < Nreal) Cf[(size_t)m * Nreal + n] = v + b0[n];
                } else {
                    int which = n >> 8, idx = n & 255;
                    int hh = idx >> 5, d = idx & 31;
                    int s = m & (SEQ - 1), b = m >> 11;
                    if (which == 0)
                        Cb[(((size_t)(b * NHD + hh)) * SEQ + s) * DHD + d] =
                            f2bf((v + b0[idx]) * QPRE);
                    else if (which == 1)
                        Ck[(((size_t)(b * NHD + hh)) * SEQ + s) * DHD + d] = f2bf(v + b1[idx]);
                    else {
                        int sp = (s & ~31) | (((s & 15) << 1) | ((s >> 4) & 1));
                        Cv[(((size_t)(b * NHD + hh)) * DHD + d) * SEQ + sp] = f2bf(v + b2[idx]);
                    }
                }
            }
        }
    }
}

// ---------------------------------------------------------------------------
// MFMA flash attention v3.
// 2 waves per tile-pair (key-parity split, chunks ch = parity, parity+2, ...)
// -> grid (32,H,B)=1024 blocks, 16 waves/CU. Kerple bias+causal mask via a
// single multiplicative LDS table zero-extended for d<0:
//   e = exp2(score) * tabs[d + 64]   (tabs[i]=0 for i<64)
// so the inner loop has NO branches/guards: 1 exp2 + 1 LDS read + 1 mul.
// Packed-P (bf16x2 per b32, matching interleaved V^T). No explicit waitcnt:
// DS ops are in-order per wave; compiler inserts result waits.
// End: parity partials combined through LDS + __syncthreads.
// ---------------------------------------------------------------------------
__global__ __launch_bounds__(256) void attn_mfma(
    const ushort_t* __restrict__ qb, const ushort_t* __restrict__ kb,
    const ushort_t* __restrict__ vtb, const float* __restrict__ kp,
    const float* __restrict__ ka, ushort_t* __restrict__ ob)
{
    int h = blockIdx.y, b = blockIdx.z;
    int tid = threadIdx.x, wv = tid >> 6, lane = tid & 63;
    int quad = lane >> 4, l16 = lane & 15;
    int pair = wv >> 1, parity = wv & 1;

    __shared__ float tabs[2112];          // [64 zeros | w(d), d=0..2047]
    __shared__ ushort_t P2[4][2][16 * 40];
    __shared__ float Cmb[2][64][28];

    float p = log1pf(__expf(kp[h]));      // softplus
    float a = log1pf(__expf(ka[h]));
    for (int i = tid; i < 2112; i += 256) {
        float w = 0.0f;
        if (i >= 64) w = exp2f(-p * __log2f(fmaf(a, (float)(i - 64), 1.0f)));
        tabs[i] = w;
    }
    __syncthreads();

    int bh = b * NHD + h;
    const ushort_t* Qh = qb + (size_t)bh * SEQ * DHD;
    const ushort_t* Kh = kb + (size_t)bh * SEQ * DHD;
    const ushort_t* Vh = vtb + (size_t)bh * DHD * SEQ;

    int pj = blockIdx.x * 2 + pair;       // 0..63
    int tlo = pj, thi = 127 - pj;
    int qlo0 = tlo * 16, qhi0 = thi * 16;

    short8 qfl = *(const short8*)&Qh[(qlo0 + l16) * DHD + quad * 8];
    short8 qfh = *(const short8*)&Qh[(qhi0 + l16) * DHD + quad * 8];
    f32x4 ol0 = (f32x4){0.f,0.f,0.f,0.f}, ol1 = (f32x4){0.f,0.f,0.f,0.f};
    f32x4 oh0 = (f32x4){0.f,0.f,0.f,0.f}, oh1 = (f32x4){0.f,0.f,0.f,0.f};
    float lsl[4] = {0.f,0.f,0.f,0.f}, lsh[4] = {0.f,0.f,0.f,0.f};
    ushort_t* Pl = &P2[wv][0][0];
    ushort_t* Ph = &P2[wv][1][0];

    int nch_hi = (thi + 2) >> 1;
    int nch_lo = (tlo + 2) >> 1;
    int qsrh = qhi0 + quad * 4;
    int qsrl = qlo0 + quad * 4;

    for (int ch = parity; ch < nch_hi; ch += 2) {
        int k0 = ch * 32;
        short8 kf0 = *(const short8*)&Kh[(k0 + l16) * DHD + quad * 8];
        short8 kf1 = *(const short8*)&Kh[(k0 + 16 + l16) * DHD + quad * 8];
        short8 vf0 = *(const short8*)&Vh[l16 * SEQ + k0 + quad * 8];
        short8 vf1 = *(const short8*)&Vh[(16 + l16) * SEQ + k0 + quad * 8];
        f32x4 z = (f32x4){0.f,0.f,0.f,0.f};

        // ---- hi tile ----
        f32x4 s0 = __builtin_amdgcn_mfma_f32_16x16x32_bf16(qfh, kf0, z, 0, 0, 0);
        f32x4 s1 = __builtin_amdgcn_mfma_f32_16x16x32_bf16(qfh, kf1, z, 0, 0, 0);
        {
            const float* tp = &tabs[qsrh - k0 - l16 + 48];  // tp[r]=w(d-16), tp[16+r]=w(d)
#pragma unroll
            for (int r = 0; r < 4; r++) {
                float e0 = exp2f(s0[r]) * tp[16 + r];
                float e1 = exp2f(s1[r]) * tp[r];
                lsh[r] += e0 + e1;
                *(unsigned*)&Ph[(quad * 4 + r) * 40 + l16 * 2] = pack_bf16(e0, e1);
            }
        }
        // ---- lo tile (shares K/V frags) ----
        bool do_lo = (ch < nch_lo);
        if (do_lo) {
            f32x4 t0 = __builtin_amdgcn_mfma_f32_16x16x32_bf16(qfl, kf0, z, 0, 0, 0);
            f32x4 t1 = __builtin_amdgcn_mfma_f32_16x16x32_bf16(qfl, kf1, z, 0, 0, 0);
            const float* tq = &tabs[qsrl - k0 - l16 + 48];
#pragma unroll
            for (int r = 0; r < 4; r++) {
                float e0 = exp2f(t0[r]) * tq[16 + r];
                float e1 = exp2f(t1[r]) * tq[r];
                lsl[r] += e0 + e1;
                *(unsigned*)&Pl[(quad * 4 + r) * 40 + l16 * 2] = pack_bf16(e0, e1);
            }
        }

        __builtin_amdgcn_wave_barrier();   // keep write->read program order
        short8 pfh = *(const short8*)&Ph[l16 * 40 + quad * 8];
        oh0 = __builtin_amdgcn_mfma_f32_16x16x32_bf16(pfh, vf0, oh0, 0, 0, 0);
        oh1 = __builtin_amdgcn_mfma_f32_16x16x32_bf16(pfh, vf1, oh1, 0, 0, 0);
        if (do_lo) {
            short8 pfl = *(const short8*)&Pl[l16 * 40 + quad * 8];
            ol0 = __builtin_amdgcn_mfma_f32_16x16x32_bf16(pfl, vf0, ol0, 0, 0, 0);
            ol1 = __builtin_amdgcn_mfma_f32_16x16x32_bf16(pfl, vf1, ol1, 0, 0, 0);
        }
    }

    // ---- combine parity partials ----
    if (parity == 1) {
        float* cp = &Cmb[pair][lane][0];
        *(float4*)&cp[0]  = (float4){oh0[0], oh0[1], oh0[2], oh0[3]};
        *(float4*)&cp[4]  = (float4){oh1[0], oh1[1], oh1[2], oh1[3]};
        *(float4*)&cp[8]  = (float4){ol0[0], ol0[1], ol0[2], ol0[3]};
        *(float4*)&cp[12] = (float4){ol1[0], ol1[1], ol1[2], ol1[3]};
        *(float4*)&cp[16] = (float4){lsh[0], lsh[1], lsh[2], lsh[3]};
        *(float4*)&cp[20] = (float4){lsl[0], lsl[1], lsl[2], lsl[3]};
    }
    __syncthreads();
    if (parity == 0) {
        const float* cp = &Cmb[pair][lane][0];
#pragma unroll
        for (int i = 0; i < 4; i++) {
            oh0[i] += cp[i];      oh1[i] += cp[4 + i];
            ol0[i] += cp[8 + i];  ol1[i] += cp[12 + i];
            lsh[i] += cp[16 + i]; lsl[i] += cp[20 + i];
        }
#pragma unroll
        for (int r = 0; r < 4; r++) {
#pragma unroll
            for (int off = 1; off < 16; off <<= 1) {
                lsh[r] += __shfl_xor(lsh[r], off, 16);
                lsl[r] += __shfl_xor(lsl[r], off, 16);
            }
        }
#pragma unroll
        for (int r = 0; r < 4; r++) {
            float rh = 1.0f / lsh[r];
            float rl = 1.0f / lsl[r];
            size_t bh_ = ((size_t)(b * SEQ + qsrh + r)) * DM + h * DHD;
            size_t bl_ = ((size_t)(b * SEQ + qsrl + r)) * DM + h * DHD;
            ob[bh_ + l16]      = f2bf(oh0[r] * rh);
            ob[bh_ + 16 + l16] = f2bf(oh1[r] * rh);
            ob[bl_ + l16]      = f2bf(ol0[r] * rl);
            ob[bl_ + 16 + l16] = f2bf(ol1[r] * rl);
        }
    }
}

// ---------------------------------------------------------------------------
extern "C" void kernel_launch(void* const* d_in, const int* in_sizes, int n_in,
                              void* d_out, int out_size, void* d_ws, size_t ws_size,
                              hipStream_t stream) {
    const int*   interactions = (const int*)d_in[0];
    const int*   patterns     = (const int*)d_in[1];
    const float* ff           = (const float*)d_in[2];
    const float* inter_emb    = (const float*)d_in[3];
    const float* pattern_emb  = (const float*)d_in[4];
    const float* feat_W       = (const float*)d_in[5];
    const float* feat_b       = (const float*)d_in[6];
    const float* in_W         = (const float*)d_in[7];
    const float* in_b         = (const float*)d_in[8];
    const float* time_W       = (const float*)d_in[9];
    const float* time_b       = (const float*)d_in[10];
    const float* pos_W        = (const float*)d_in[11];
    const float* pos_b        = (const float*)d_in[12];
    const float* Wq           = (const float*)d_in[13];
    const float* bq           = (const float*)d_in[14];
    const float* Wk           = (const float*)d_in[15];
    const float* bk           = (const float*)d_in[16];
    const float* Wv           = (const float*)d_in[17];
    const float* bv           = (const float*)d_in[18];
    const float* Wo           = (const float*)d_in[19];
    const float* bo           = (const float*)d_in[20];
    const float* kerple_p     = (const float*)d_in[21];
    const float* kerple_a     = (const float*)d_in[22];
    const float* ln1_g        = (const float*)d_in[23];
    const float* ln1_b        = (const float*)d_in[24];
    const float* ln2_g        = (const float*)d_in[25];
    const float* ln2_b        = (const float*)d_in[26];
    const float* ffn_W1       = (const float*)d_in[27];
    const float* ffn_b1       = (const float*)d_in[28];
    const float* ffn_W2       = (const float*)d_in[29];
    const float* ffn_b2       = (const float*)d_in[30];
    const float* out_W        = (const float*)d_in[31];
    const float* out_b        = (const float*)d_in[32];
    float* out = (float*)d_out;

    // ---- workspace layout (bytes) ----
    char* wsb = (char*)d_ws;
    const size_t MB = 1024 * 1024;
    float*    x    = (float*)(wsb + 0);          //  8 MB fp32 activations
    ushort_t* tmpb = (ushort_t*)(wsb + 8  * MB); //  4 MB bf16 residual branch
    ushort_t* xb   = (ushort_t*)(wsb + 16 * MB); //  4 MB bf16 copy of x
    ushort_t* qbuf = (ushort_t*)(wsb + 20 * MB); //  4 MB bf16 Q (B,H,S,DH), pre-scaled
    ushort_t* kbuf = (ushort_t*)(wsb + 24 * MB); //  4 MB bf16 K (B,H,S,DH)
    ushort_t* vtbf = (ushort_t*)(wsb + 28 * MB); //  4 MB bf16 V^T (B,H,DH,S) interleaved
    ushort_t* shrd = (ushort_t*)(wsb + 32 * MB); // 16 MB: cbuf / o_bf / h_bf
    ushort_t* cbuf = shrd;                        // 8192x384 bf16
    ushort_t* o_bf = shrd;                        // 8192x256 bf16
    ushort_t* h_bf = shrd;                        // 8192x1024 bf16
    char* wp = wsb + 48 * MB;
    ushort_t* inWt  = (ushort_t*)wp;  wp += 256  * 384 * 2;       // [256][384]
    ushort_t* qkvWt = (ushort_t*)wp;  wp += 2 * 768 * 256 * 2;    // [l][768][256]
    ushort_t* WoT   = (ushort_t*)wp;  wp += 2 * 256 * 256 * 2;    // [l][256][256]
    ushort_t* W1T   = (ushort_t*)wp;  wp += 2 * 1024 * 256 * 2;   // [l][1024][256]
    ushort_t* W2T   = (ushort_t*)wp;  wp += 2 * 256 * 1024 * 2;   // [l][256][1024]
    ushort_t* outWt = (ushort_t*)wp;  wp += 2048 * 256 * 2;       // [2048][256] zero-pad

    // ---- weight conversion (exact tile grid) ----
    ConvArgs ca;
    int D2 = 256 * 256;
    int base = 0, ib = 0;
    auto addseg = [&](const float* src, ushort_t* dst, int K, int N, int Npad) {
        ca.s[ib].src = src; ca.s[ib].dst = dst; ca.s[ib].K = K; ca.s[ib].N = N;
        ca.s[ib].ntx = Npad / 32; ca.s[ib].base = base;
        base += (Npad / 32) * (K / 32); ib++;
    };
    addseg(in_W,            inWt,           384,  256,  256);
    addseg(Wq,              qkvWt,          256,  256,  256);
    addseg(Wk,              qkvWt + 1 * D2, 256,  256,  256);
    addseg(Wv,              qkvWt + 2 * D2, 256,  256,  256);
    addseg(Wq + D2,         qkvWt + 3 * D2, 256,  256,  256);
    addseg(Wk + D2,         qkvWt + 4 * D2, 256,  256,  256);
    addseg(Wv + D2,         qkvWt + 5 * D2, 256,  256,  256);
    addseg(Wo,              WoT,            256,  256,  256);
    addseg(Wo + D2,         WoT + D2,       256,  256,  256);
    addseg(ffn_W1,          W1T,            256,  1024, 1024);
    addseg(ffn_W1 + 4 * D2, W1T + 4 * D2,   256,  1024, 1024);
    addseg(ffn_W2,          W2T,            1024, 256,  256);
    addseg(ffn_W2 + 4 * D2, W2T + 4 * D2,   1024, 256,  256);
    addseg(out_W,           outWt,          256,  2000, 2048);
    convert_kernel<<<base, 256, 0, stream>>>(ca);

    // ---- input projection (+ fused time/pos encodings) ----
    concat_kernel<<<NTOK, 384, 0, stream>>>(interactions, patterns, ff,
                                            inter_emb, pattern_emb, feat_W, feat_b, cbuf);
    gemm64<<<dim3(4, 128), 256, 0, stream>>>(cbuf, inWt, NTOK, 256, 384, 4,
                                             x, xb, in_b, ff, time_W, time_b, pos_W, pos_b);

    for (int l = 0; l < 2; l++) {
        gemm_bf16_128<<<dim3(6, 64), 256, 0, stream>>>(
            xb, qkvWt + (size_t)l * 768 * 256, NTOK, 768, 256, 2,
            nullptr, qbuf, kbuf, vtbf,
            bq + l * 256, bk + l * 256, bv + l * 256, 0);
        attn_mfma<<<dim3(32, NHD, BATCH), 256, 0, stream>>>(
            qbuf, kbuf, vtbf, kerple_p + l * NHD, kerple_a + l * NHD, o_bf);
        gemm64<<<dim3(4, 128), 256, 0, stream>>>(
            o_bf, WoT + (size_t)l * D2, NTOK, 256, 256, 5,
            nullptr, tmpb, bo + l * 256, nullptr, nullptr, nullptr, nullptr, nullptr);
        ln_kernel<<<NTOK, 256, 0, stream>>>(x, tmpb, ln1_g + l * 256, ln1_b + l * 256, xb);
        gemm_bf16_128<<<dim3(8, 64), 256, 0, stream>>>(
            xb, W1T + (size_t)l * 4 * D2, NTOK, 1024, 256, 1,
            nullptr, h_bf, nullptr, nullptr, ffn_b1 + l * 1024, nullptr, nullptr, 0);
        gemm64<<<dim3(4, 128), 256, 0, stream>>>(
            h_bf, W2T + (size_t)l * 4 * D2, NTOK, 256, 1024, 5,
            nullptr, tmpb, ffn_b2 + l * 256, nullptr, nullptr, nullptr, nullptr, nullptr);
        ln_kernel<<<NTOK, 256, 0, stream>>>(x, tmpb, ln2_g + l * 256, ln2_b + l * 256, xb);
    }

    // ---- output projection (N=2048 padded, guard to 2000) ----
    gemm_bf16_128<<<dim3(16, 64), 256, 0, stream>>>(
        xb, outWt, NTOK, 2048, 256, 3,
        out, nullptr, nullptr, nullptr, out_b, nullptr, nullptr, NSKC);
}

// Round 7
// 450.498 us; speedup vs baseline: 1.0848x; 1.0724x over previous
//
#include <hip/hip_runtime.h>
#include <math.h>

// B=4, S=2048, F=8, D=256, H=8, L=2, FF=1024, NSK=2000
#define SEQ   2048
#define BATCH 4
#define NTOK  8192
#define DM    256
#define NHD   8
#define DHD   32
#define DFF   1024
#define NSKC  2000

typedef __attribute__((ext_vector_type(8))) short short8;
typedef __attribute__((ext_vector_type(4))) float f32x4;
typedef unsigned short ushort_t;

// 1/sqrt(32) * log2(e): folded into Q so scores come out in exp2 domain.
#define QPRE ((float)(0.17677669529663687 * 1.4426950408889634))

// pair-interleave permutation within each 32-element block:
// logical i -> stored (i&~31) | ((i&15)<<1) | ((i>>4)&1)
#define SPERM(i) (((i) & ~31) | (((i) & 15) << 1) | (((i) >> 4) & 1))

__device__ __forceinline__ ushort_t f2bf(float x) {
    union { float f; unsigned u; } c; c.f = x;
    unsigned r = c.u + 0x7FFFu + ((c.u >> 16) & 1u);
    return (ushort_t)(r >> 16);
}

#if __has_builtin(__builtin_amdgcn_cvt_pk_bf16_f32)
typedef __attribute__((ext_vector_type(2))) __bf16 bf16x2_t;
__device__ __forceinline__ unsigned pack_bf16(float a, float b) {
    bf16x2_t r = __builtin_amdgcn_cvt_pk_bf16_f32(a, b);
    union { bf16x2_t v; unsigned u; } c; c.v = r;
    return c.u;
}
#else
__device__ __forceinline__ unsigned pack_bf16(float a, float b) {
    return (unsigned)f2bf(a) | ((unsigned)f2bf(b) << 16);
}
#endif

__device__ __forceinline__ float bf2f(ushort_t x) {
    union { unsigned u; float f; } c; c.u = ((unsigned)x) << 16;
    return c.f;
}

// ---------------------------------------------------------------------------
// Weight conversion, exact tile grid: dst[n][kperm(k)] = bf16(src[k][n]).
// kperm pair-interleaves k within 32-blocks to match packed activations.
// ---------------------------------------------------------------------------
struct ConvSeg { const float* src; ushort_t* dst; int K; int N; int ntx; int base; int kperm; };
struct ConvArgs { ConvSeg s[14]; };

__global__ __launch_bounds__(256) void convert_kernel(ConvArgs args) {
    int bid = blockIdx.x;
    int si = 0;
#pragma unroll
    for (int i = 1; i < 14; i++) if (bid >= args.s[i].base) si = i;
    ConvSeg sg = args.s[si];
    int local = bid - sg.base;
    int ty = local / sg.ntx;
    int tx = local - ty * sg.ntx;
    int n0 = tx * 32, k0 = ty * 32;
    __shared__ float T[32][33];
    int tid = threadIdx.x;
    int tn = tid & 31, tk4 = tid >> 5;
#pragma unroll
    for (int i = 0; i < 4; i++) {
        int kl = tk4 + i * 8;
        float v = 0.0f;
        if (n0 + tn < sg.N) v = sg.src[(size_t)(k0 + kl) * sg.N + n0 + tn];
        T[kl][tn] = v;
    }
    __syncthreads();
    int tk = tid & 31, tn4 = tid >> 5;
    int tks = sg.kperm ? (((tk & 15) << 1) | ((tk >> 4) & 1)) : tk;
#pragma unroll
    for (int i = 0; i < 4; i++) {
        int nl = tn4 + i * 8;
        sg.dst[(size_t)(n0 + nl) * sg.K + k0 + tks] = f2bf(T[tk][nl]);
    }
}

// ---------------------------------------------------------------------------
// concat row [inter_e(256) | pat_e(64) | feat_e(64)] -> bf16 (plain layout)
// ---------------------------------------------------------------------------
__global__ __launch_bounds__(384) void concat_kernel(
    const int* __restrict__ interactions, const int* __restrict__ patterns,
    const float* __restrict__ ff, const float* __restrict__ inter_emb,
    const float* __restrict__ pattern_emb, const float* __restrict__ feat_W,
    const float* __restrict__ feat_b, ushort_t* __restrict__ out)
{
    int tok = blockIdx.x;
    int j = threadIdx.x;
    float v;
    if (j < 256) {
        v = inter_emb[(size_t)interactions[tok] * 256 + j];
    } else if (j < 320) {
        v = pattern_emb[patterns[tok] * 64 + (j - 256)];
    } else {
        int c = j - 320;
        float acc = feat_b[c];
#pragma unroll
        for (int f = 0; f < 8; f++) acc += ff[tok * 8 + f] * feat_W[f * 64 + c];
        v = acc;
    }
    out[(size_t)tok * 384 + j] = f2bf(v);
}

// ---------------------------------------------------------------------------
// LayerNorm(x + r) in place. r and xb are in pair-interleaved bf16 layout;
// x fp32 is plain. Thread d handles logical dim d at stored index SPERM(d).
// ---------------------------------------------------------------------------
__global__ __launch_bounds__(256) void ln_kernel(
    float* __restrict__ x, const ushort_t* __restrict__ r,
    const float* __restrict__ g, const float* __restrict__ b,
    ushort_t* __restrict__ xb)
{
    int tok = blockIdx.x;
    int d = threadIdx.x;
    int ds = SPERM(d);
    size_t row = (size_t)tok * DM;
    float v = x[row + d] + bf2f(r[row + ds]);
    float s1 = v, s2 = v * v;
#pragma unroll
    for (int off = 32; off > 0; off >>= 1) {
        s1 += __shfl_down(s1, off, 64);
        s2 += __shfl_down(s2, off, 64);
    }
    __shared__ float red1[4], red2[4];
    int wid = d >> 6, lane = d & 63;
    if (lane == 0) { red1[wid] = s1; red2[wid] = s2; }
    __syncthreads();
    s1 = red1[0] + red1[1] + red1[2] + red1[3];
    s2 = red2[0] + red2[1] + red2[2] + red2[3];
    float mean = s1 * (1.0f / 256.0f);
    float var = s2 * (1.0f / 256.0f) - mean * mean;
    float inv = rsqrtf(var + 1e-6f);
    float nv = g[d] * (v - mean) * inv + b[d];
    x[row + d] = nv;
    xb[row + ds] = f2bf(nv);
}

// ---------------------------------------------------------------------------
// bf16 MFMA GEMM, BM=64 BN=64 BK=32: 4 waves, each 16x64, 4 mfma/iter.
// Grid: blockIdx.x = m-tile (fast dim -> A-panel sharers land on one XCD),
//       blockIdx.y = n-tile.
// mode 4: in-proj epilogue (bias + time/pos enc) -> x fp32 plain + xb packed
// mode 5: packed bf16 out + bias (residual branches)
// ---------------------------------------------------------------------------
__global__ __launch_bounds__(256) void gemm64(
    const ushort_t* __restrict__ A, const ushort_t* __restrict__ Bt,
    int M, int N, int K, int mode,
    float* __restrict__ Cf, ushort_t* __restrict__ Cb,
    const float* __restrict__ b0,
    const float* __restrict__ ffg, const float* __restrict__ tW,
    const float* __restrict__ tb, const float* __restrict__ pW,
    const float* __restrict__ pb)
{
    __shared__ ushort_t As[64][40];
    __shared__ ushort_t Bs[64][40];
    int m0 = blockIdx.x * 64, n0 = blockIdx.y * 64;
    int tid = threadIdx.x;
    int wv = tid >> 6, lane = tid & 63;
    int quad = lane >> 4, l16 = lane & 15;
    int srow = tid >> 2, sc = (tid & 3) << 3;

    f32x4 acc[4];
#pragma unroll
    for (int j = 0; j < 4; j++) acc[j] = (f32x4){0.f, 0.f, 0.f, 0.f};

    uint4 pa = *(const uint4*)&A[(size_t)(m0 + srow) * K + sc];
    uint4 pbv = *(const uint4*)&Bt[(size_t)(n0 + srow) * K + sc];

    int mrow = wv * 16;
    for (int k0 = 0; k0 < K; k0 += 32) {
        __syncthreads();
        *(uint4*)&As[srow][sc] = pa;
        *(uint4*)&Bs[srow][sc] = pbv;
        __syncthreads();
        if (k0 + 32 < K) {
            pa = *(const uint4*)&A[(size_t)(m0 + srow) * K + k0 + 32 + sc];
            pbv = *(const uint4*)&Bt[(size_t)(n0 + srow) * K + k0 + 32 + sc];
        }
        short8 af = *(const short8*)&As[mrow + l16][quad * 8];
        short8 bf0 = *(const short8*)&Bs[l16][quad * 8];
        short8 bf1 = *(const short8*)&Bs[16 + l16][quad * 8];
        short8 bf2 = *(const short8*)&Bs[32 + l16][quad * 8];
        short8 bf3 = *(const short8*)&Bs[48 + l16][quad * 8];
        acc[0] = __builtin_amdgcn_mfma_f32_16x16x32_bf16(af, bf0, acc[0], 0, 0, 0);
        acc[1] = __builtin_amdgcn_mfma_f32_16x16x32_bf16(af, bf1, acc[1], 0, 0, 0);
        acc[2] = __builtin_amdgcn_mfma_f32_16x16x32_bf16(af, bf2, acc[2], 0, 0, 0);
        acc[3] = __builtin_amdgcn_mfma_f32_16x16x32_bf16(af, bf3, acc[3], 0, 0, 0);
    }

#pragma unroll
    for (int r = 0; r < 4; r++) {
        int m = m0 + mrow + quad * 4 + r;
        if (mode == 4) {
            int s = m & (SEQ - 1);
            float el = ffg[m * 8];
            float pos = (float)s * (1.0f / (float)SEQ);
#pragma unroll
            for (int nt = 0; nt < 4; nt += 2) {
                int nlo = n0 + nt * 16 + l16;
                int nhi = nlo + 16;
                float v0 = acc[nt][r] + b0[nlo] + tanhf(el * tW[nlo] + tb[nlo]) + pos * pW[nlo] + pb[nlo];
                float v1 = acc[nt + 1][r] + b0[nhi] + tanhf(el * tW[nhi] + tb[nhi]) + pos * pW[nhi] + pb[nhi];
                Cf[(size_t)m * N + nlo] = v0;
                Cf[(size_t)m * N + nhi] = v1;
                *(unsigned*)&Cb[(size_t)m * N + n0 + nt * 16 + 2 * l16] = pack_bf16(v0, v1);
            }
        } else {
#pragma unroll
            for (int nt = 0; nt < 4; nt += 2) {
                int nlo = n0 + nt * 16 + l16;
                float v0 = acc[nt][r] + b0[nlo];
                float v1 = acc[nt + 1][r] + b0[nlo + 16];
                *(unsigned*)&Cb[(size_t)m * N + n0 + nt * 16 + 2 * l16] = pack_bf16(v0, v1);
            }
        }
    }
}

// ---------------------------------------------------------------------------
// bf16 MFMA GEMM, BM=128 BN=128 BK=32: 4 waves, each 64x64, 16 mfma/iter.
// Grid: blockIdx.x = m-tile (fast), blockIdx.y = n-tile.
// mode 1: gelu -> packed bf16 out
// mode 2: QKV epilogue: q (pre-scaled), k -> (B,H,S,DH) packed-pair bf16;
//         v -> V^T (B,H,DH,S) with pair-interleaved s-columns
// mode 3: fp32 + bias plain, col guard n < Nreal
// ---------------------------------------------------------------------------
__global__ __launch_bounds__(256) void gemm_bf16_128(
    const ushort_t* __restrict__ A, const ushort_t* __restrict__ Bt,
    int M, int N, int K, int mode,
    float* __restrict__ Cf, ushort_t* __restrict__ Cb,
    ushort_t* __restrict__ Ck, ushort_t* __restrict__ Cv,
    const float* __restrict__ b0, const float* __restrict__ b1,
    const float* __restrict__ b2, int Nreal)
{
    __shared__ ushort_t As[128][40];
    __shared__ ushort_t Bs[128][40];
    int m0 = blockIdx.x * 128, n0 = blockIdx.y * 128;
    int tid = threadIdx.x;
    int wv = tid >> 6, lane = tid & 63;
    int quad = lane >> 4, l16 = lane & 15;
    int wm = (wv >> 1) * 64, wn = (wv & 1) * 64;
    int srow = tid >> 1, sc = (tid & 1) << 4;

    f32x4 acc[4][4];
#pragma unroll
    for (int i = 0; i < 4; i++)
#pragma unroll
        for (int j = 0; j < 4; j++) acc[i][j] = (f32x4){0.f, 0.f, 0.f, 0.f};

    uint4 pa0 = *(const uint4*)&A[(size_t)(m0 + srow) * K + sc];
    uint4 pa1 = *(const uint4*)&A[(size_t)(m0 + srow) * K + sc + 8];
    uint4 pb0 = *(const uint4*)&Bt[(size_t)(n0 + srow) * K + sc];
    uint4 pb1 = *(const uint4*)&Bt[(size_t)(n0 + srow) * K + sc + 8];

    for (int k0 = 0; k0 < K; k0 += 32) {
        __syncthreads();
        *(uint4*)&As[srow][sc] = pa0;
        *(uint4*)&As[srow][sc + 8] = pa1;
        *(uint4*)&Bs[srow][sc] = pb0;
        *(uint4*)&Bs[srow][sc + 8] = pb1;
        __syncthreads();
        if (k0 + 32 < K) {
            pa0 = *(const uint4*)&A[(size_t)(m0 + srow) * K + k0 + 32 + sc];
            pa1 = *(const uint4*)&A[(size_t)(m0 + srow) * K + k0 + 32 + sc + 8];
            pb0 = *(const uint4*)&Bt[(size_t)(n0 + srow) * K + k0 + 32 + sc];
            pb1 = *(const uint4*)&Bt[(size_t)(n0 + srow) * K + k0 + 32 + sc + 8];
        }
        short8 af[4], bf[4];
#pragma unroll
        for (int i = 0; i < 4; i++) {
            af[i] = *(const short8*)&As[wm + i * 16 + l16][quad * 8];
            bf[i] = *(const short8*)&Bs[wn + i * 16 + l16][quad * 8];
        }
#pragma unroll
        for (int i = 0; i < 4; i++)
#pragma unroll
            for (int j = 0; j < 4; j++)
                acc[i][j] = __builtin_amdgcn_mfma_f32_16x16x32_bf16(af[i], bf[j], acc[i][j], 0, 0, 0);
    }

#pragma unroll
    for (int i = 0; i < 4; i++) {
#pragma unroll
        for (int jp = 0; jp < 4; jp += 2) {
            int nlo = n0 + wn + jp * 16 + l16;   // pair partner is nlo+16
#pragma unroll
            for (int r = 0; r < 4; r++) {
                int m = m0 + wm + i * 16 + quad * 4 + r;
                float vlo = acc[i][jp][r];
                float vhi = acc[i][jp + 1][r];
                if (mode == 1) {
                    float t0 = vlo + b0[nlo];
                    float t1 = vhi + b0[nlo + 16];
                    t0 = 0.5f * t0 * (1.0f + erff(t0 * 0.70710678118654752f));
                    t1 = 0.5f * t1 * (1.0f + erff(t1 * 0.70710678118654752f));
                    *(unsigned*)&Cb[(size_t)m * N + n0 + wn + jp * 16 + 2 * l16] = pack_bf16(t0, t1);
                } else if (mode == 3) {
                    if (nlo < Nreal)      Cf[(size_t)m * Nreal + nlo] = vlo + b0[nlo];
                    if (nlo + 16 < Nreal) Cf[(size_t)m * Nreal + nlo + 16] = vhi + b0[nlo + 16];
                } else {
                    int which = nlo >> 8, idx = nlo & 255;
                    int hh = idx >> 5, d = idx & 31;      // d = l16 (+16 for hi)
                    int s = m & (SEQ - 1), b = m >> 11;
                    if (which == 0) {
                        float q0 = (vlo + b0[idx]) * QPRE;
                        float q1 = (vhi + b0[idx + 16]) * QPRE;
                        *(unsigned*)&Cb[(((size_t)(b * NHD + hh)) * SEQ + s) * DHD + 2 * d] = pack_bf16(q0, q1);
                    } else if (which == 1) {
                        float k0v = vlo + b1[idx];
                        float k1v = vhi + b1[idx + 16];
                        *(unsigned*)&Ck[(((size_t)(b * NHD + hh)) * SEQ + s) * DHD + 2 * d] = pack_bf16(k0v, k1v);
                    } else {
                        int sp = (s & ~31) | (((s & 15) << 1) | ((s >> 4) & 1));
                        Cv[(((size_t)(b * NHD + hh)) * DHD + d) * SEQ + sp] = f2bf(vlo + b2[idx]);
                        Cv[(((size_t)(b * NHD + hh)) * DHD + d + 16) * SEQ + sp] = f2bf(vhi + b2[idx + 16]);
                    }
                }
            }
        }
    }
}

// ---------------------------------------------------------------------------
// MFMA flash attention (as R6: parity-split waves, multiplicative bias table,
// packed P + interleaved V^T). Q,K are d-pair-interleaved (consistent for the
// QK dot). O written as packed dwords in d-pair-interleaved layout (WoT k-perm
// compensates).
// ---------------------------------------------------------------------------
__global__ __launch_bounds__(256) void attn_mfma(
    const ushort_t* __restrict__ qb, const ushort_t* __restrict__ kb,
    const ushort_t* __restrict__ vtb, const float* __restrict__ kp,
    const float* __restrict__ ka, ushort_t* __restrict__ ob)
{
    int h = blockIdx.y, b = blockIdx.z;
    int tid = threadIdx.x, wv = tid >> 6, lane = tid & 63;
    int quad = lane >> 4, l16 = lane & 15;
    int pair = wv >> 1, parity = wv & 1;

    __shared__ float tabs[2112];          // [64 zeros | w(d), d=0..2047]
    __shared__ ushort_t P2[4][2][16 * 40];
    __shared__ float Cmb[2][64][28];

    float p = log1pf(__expf(kp[h]));      // softplus
    float a = log1pf(__expf(ka[h]));
    for (int i = tid; i < 2112; i += 256) {
        float w = 0.0f;
        if (i >= 64) w = exp2f(-p * __log2f(fmaf(a, (float)(i - 64), 1.0f)));
        tabs[i] = w;
    }
    __syncthreads();

    int bh = b * NHD + h;
    const ushort_t* Qh = qb + (size_t)bh * SEQ * DHD;
    const ushort_t* Kh = kb + (size_t)bh * SEQ * DHD;
    const ushort_t* Vh = vtb + (size_t)bh * DHD * SEQ;

    int pj = blockIdx.x * 2 + pair;       // 0..63
    int tlo = pj, thi = 127 - pj;
    int qlo0 = tlo * 16, qhi0 = thi * 16;

    short8 qfl = *(const short8*)&Qh[(qlo0 + l16) * DHD + quad * 8];
    short8 qfh = *(const short8*)&Qh[(qhi0 + l16) * DHD + quad * 8];
    f32x4 ol0 = (f32x4){0.f,0.f,0.f,0.f}, ol1 = (f32x4){0.f,0.f,0.f,0.f};
    f32x4 oh0 = (f32x4){0.f,0.f,0.f,0.f}, oh1 = (f32x4){0.f,0.f,0.f,0.f};
    float lsl[4] = {0.f,0.f,0.f,0.f}, lsh[4] = {0.f,0.f,0.f,0.f};
    ushort_t* Pl = &P2[wv][0][0];
    ushort_t* Ph = &P2[wv][1][0];

    int nch_hi = (thi + 2) >> 1;
    int nch_lo = (tlo + 2) >> 1;
    int qsrh = qhi0 + quad * 4;
    int qsrl = qlo0 + quad * 4;

    for (int ch = parity; ch < nch_hi; ch += 2) {
        int k0 = ch * 32;
        short8 kf0 = *(const short8*)&Kh[(k0 + l16) * DHD + quad * 8];
        short8 kf1 = *(const short8*)&Kh[(k0 + 16 + l16) * DHD + quad * 8];
        short8 vf0 = *(const short8*)&Vh[l16 * SEQ + k0 + quad * 8];
        short8 vf1 = *(const short8*)&Vh[(16 + l16) * SEQ + k0 + quad * 8];
        f32x4 z = (f32x4){0.f,0.f,0.f,0.f};

        f32x4 s0 = __builtin_amdgcn_mfma_f32_16x16x32_bf16(qfh, kf0, z, 0, 0, 0);
        f32x4 s1 = __builtin_amdgcn_mfma_f32_16x16x32_bf16(qfh, kf1, z, 0, 0, 0);
        {
            const float* tp = &tabs[qsrh - k0 - l16 + 48];
#pragma unroll
            for (int r = 0; r < 4; r++) {
                float e0 = exp2f(s0[r]) * tp[16 + r];
                float e1 = exp2f(s1[r]) * tp[r];
                lsh[r] += e0 + e1;
                *(unsigned*)&Ph[(quad * 4 + r) * 40 + l16 * 2] = pack_bf16(e0, e1);
            }
        }
        bool do_lo = (ch < nch_lo);
        if (do_lo) {
            f32x4 t0 = __builtin_amdgcn_mfma_f32_16x16x32_bf16(qfl, kf0, z, 0, 0, 0);
            f32x4 t1 = __builtin_amdgcn_mfma_f32_16x16x32_bf16(qfl, kf1, z, 0, 0, 0);
            const float* tq = &tabs[qsrl - k0 - l16 + 48];
#pragma unroll
            for (int r = 0; r < 4; r++) {
                float e0 = exp2f(t0[r]) * tq[16 + r];
                float e1 = exp2f(t1[r]) * tq[r];
                lsl[r] += e0 + e1;
                *(unsigned*)&Pl[(quad * 4 + r) * 40 + l16 * 2] = pack_bf16(e0, e1);
            }
        }

        __builtin_amdgcn_wave_barrier();
        short8 pfh = *(const short8*)&Ph[l16 * 40 + quad * 8];
        oh0 = __builtin_amdgcn_mfma_f32_16x16x32_bf16(pfh, vf0, oh0, 0, 0, 0);
        oh1 = __builtin_amdgcn_mfma_f32_16x16x32_bf16(pfh, vf1, oh1, 0, 0, 0);
        if (do_lo) {
            short8 pfl = *(const short8*)&Pl[l16 * 40 + quad * 8];
            ol0 = __builtin_amdgcn_mfma_f32_16x16x32_bf16(pfl, vf0, ol0, 0, 0, 0);
            ol1 = __builtin_amdgcn_mfma_f32_16x16x32_bf16(pfl, vf1, ol1, 0, 0, 0);
        }
    }

    if (parity == 1) {
        float* cp = &Cmb[pair][lane][0];
        *(float4*)&cp[0]  = (float4){oh0[0], oh0[1], oh0[2], oh0[3]};
        *(float4*)&cp[4]  = (float4){oh1[0], oh1[1], oh1[2], oh1[3]};
        *(float4*)&cp[8]  = (float4){ol0[0], ol0[1], ol0[2], ol0[3]};
        *(float4*)&cp[12] = (float4){ol1[0], ol1[1], ol1[2], ol1[3]};
        *(float4*)&cp[16] = (float4){lsh[0], lsh[1], lsh[2], lsh[3]};
        *(float4*)&cp[20] = (float4){lsl[0], lsl[1], lsl[2], lsl[3]};
    }
    __syncthreads();
    if (parity == 0) {
        const float* cp = &Cmb[pair][lane][0];
#pragma unroll
        for (int i = 0; i < 4; i++) {
            oh0[i] += cp[i];      oh1[i] += cp[4 + i];
            ol0[i] += cp[8 + i];  ol1[i] += cp[12 + i];
            lsh[i] += cp[16 + i]; lsl[i] += cp[20 + i];
        }
#pragma unroll
        for (int r = 0; r < 4; r++) {
#pragma unroll
            for (int off = 1; off < 16; off <<= 1) {
                lsh[r] += __shfl_xor(lsh[r], off, 16);
                lsl[r] += __shfl_xor(lsl[r], off, 16);
            }
        }
#pragma unroll
        for (int r = 0; r < 4; r++) {
            float rh = 1.0f / lsh[r];
            float rl = 1.0f / lsl[r];
            size_t bh_ = ((size_t)(b * SEQ + qsrh + r)) * DM + h * DHD;
            size_t bl_ = ((size_t)(b * SEQ + qsrl + r)) * DM + h * DHD;
            *(unsigned*)&ob[bh_ + 2 * l16] = pack_bf16(oh0[r] * rh, oh1[r] * rh);
            *(unsigned*)&ob[bl_ + 2 * l16] = pack_bf16(ol0[r] * rl, ol1[r] * rl);
        }
    }
}

// ---------------------------------------------------------------------------
extern "C" void kernel_launch(void* const* d_in, const int* in_sizes, int n_in,
                              void* d_out, int out_size, void* d_ws, size_t ws_size,
                              hipStream_t stream) {
    const int*   interactions = (const int*)d_in[0];
    const int*   patterns     = (const int*)d_in[1];
    const float* ff           = (const float*)d_in[2];
    const float* inter_emb    = (const float*)d_in[3];
    const float* pattern_emb  = (const float*)d_in[4];
    const float* feat_W       = (const float*)d_in[5];
    const float* feat_b       = (const float*)d_in[6];
    const float* in_W         = (const float*)d_in[7];
    const float* in_b         = (const float*)d_in[8];
    const float* time_W       = (const float*)d_in[9];
    const float* time_b       = (const float*)d_in[10];
    const float* pos_W        = (const float*)d_in[11];
    const float* pos_b        = (const float*)d_in[12];
    const float* Wq           = (const float*)d_in[13];
    const float* bq           = (const float*)d_in[14];
    const float* Wk           = (const float*)d_in[15];
    const float* bk           = (const float*)d_in[16];
    const float* Wv           = (const float*)d_in[17];
    const float* bv           = (const float*)d_in[18];
    const float* Wo           = (const float*)d_in[19];
    const float* bo           = (const float*)d_in[20];
    const float* kerple_p     = (const float*)d_in[21];
    const float* kerple_a     = (const float*)d_in[22];
    const float* ln1_g        = (const float*)d_in[23];
    const float* ln1_b        = (const float*)d_in[24];
    const float* ln2_g        = (const float*)d_in[25];
    const float* ln2_b        = (const float*)d_in[26];
    const float* ffn_W1       = (const float*)d_in[27];
    const float* ffn_b1       = (const float*)d_in[28];
    const float* ffn_W2       = (const float*)d_in[29];
    const float* ffn_b2       = (const float*)d_in[30];
    const float* out_W        = (const float*)d_in[31];
    const float* out_b        = (const float*)d_in[32];
    float* out = (float*)d_out;

    // ---- workspace layout (bytes) ----
    char* wsb = (char*)d_ws;
    const size_t MB = 1024 * 1024;
    float*    x    = (float*)(wsb + 0);          //  8 MB fp32 activations (plain)
    ushort_t* tmpb = (ushort_t*)(wsb + 8  * MB); //  4 MB bf16 residual (perm)
    ushort_t* xb   = (ushort_t*)(wsb + 16 * MB); //  4 MB bf16 x copy (perm)
    ushort_t* qbuf = (ushort_t*)(wsb + 20 * MB); //  4 MB Q (B,H,S,DH) d-perm, pre-scaled
    ushort_t* kbuf = (ushort_t*)(wsb + 24 * MB); //  4 MB K (B,H,S,DH) d-perm
    ushort_t* vtbf = (ushort_t*)(wsb + 28 * MB); //  4 MB V^T (B,H,DH,S) s-perm
    ushort_t* shrd = (ushort_t*)(wsb + 32 * MB); // 16 MB: cbuf / o_bf / h_bf
    ushort_t* cbuf = shrd;                        // 8192x384 (plain)
    ushort_t* o_bf = shrd;                        // 8192x256 (perm)
    ushort_t* h_bf = shrd;                        // 8192x1024 (perm)
    char* wp = wsb + 48 * MB;
    ushort_t* inWt  = (ushort_t*)wp;  wp += 256  * 384 * 2;       // plain K
    ushort_t* qkvWt = (ushort_t*)wp;  wp += 2 * 768 * 256 * 2;    // K-perm
    ushort_t* WoT   = (ushort_t*)wp;  wp += 2 * 256 * 256 * 2;    // K-perm
    ushort_t* W1T   = (ushort_t*)wp;  wp += 2 * 1024 * 256 * 2;   // K-perm
    ushort_t* W2T   = (ushort_t*)wp;  wp += 2 * 256 * 1024 * 2;   // K-perm
    ushort_t* outWt = (ushort_t*)wp;  wp += 2048 * 256 * 2;       // K-perm

    // ---- weight conversion ----
    ConvArgs ca;
    int D2 = 256 * 256;
    int base = 0, ib = 0;
    auto addseg = [&](const float* src, ushort_t* dst, int K, int N, int Npad, int kp) {
        ca.s[ib].src = src; ca.s[ib].dst = dst; ca.s[ib].K = K; ca.s[ib].N = N;
        ca.s[ib].ntx = Npad / 32; ca.s[ib].base = base; ca.s[ib].kperm = kp;
        base += (Npad / 32) * (K / 32); ib++;
    };
    addseg(in_W,            inWt,           384,  256,  256,  0);
    addseg(Wq,              qkvWt,          256,  256,  256,  1);
    addseg(Wk,              qkvWt + 1 * D2, 256,  256,  256,  1);
    addseg(Wv,              qkvWt + 2 * D2, 256,  256,  256,  1);
    addseg(Wq + D2,         qkvWt + 3 * D2, 256,  256,  256,  1);
    addseg(Wk + D2,         qkvWt + 4 * D2, 256,  256,  256,  1);
    addseg(Wv + D2,         qkvWt + 5 * D2, 256,  256,  256,  1);
    addseg(Wo,              WoT,            256,  256,  256,  1);
    addseg(Wo + D2,         WoT + D2,       256,  256,  256,  1);
    addseg(ffn_W1,          W1T,            256,  1024, 1024, 1);
    addseg(ffn_W1 + 4 * D2, W1T + 4 * D2,   256,  1024, 1024, 1);
    addseg(ffn_W2,          W2T,            1024, 256,  256,  1);
    addseg(ffn_W2 + 4 * D2, W2T + 4 * D2,   1024, 256,  256,  1);
    addseg(out_W,           outWt,          256,  2000, 2048, 1);
    convert_kernel<<<base, 256, 0, stream>>>(ca);

    // ---- input projection (+ fused time/pos encodings) ----
    concat_kernel<<<NTOK, 384, 0, stream>>>(interactions, patterns, ff,
                                            inter_emb, pattern_emb, feat_W, feat_b, cbuf);
    gemm64<<<dim3(128, 4), 256, 0, stream>>>(cbuf, inWt, NTOK, 256, 384, 4,
                                             x, xb, in_b, ff, time_W, time_b, pos_W, pos_b);

    for (int l = 0; l < 2; l++) {
        gemm_bf16_128<<<dim3(64, 6), 256, 0, stream>>>(
            xb, qkvWt + (size_t)l * 768 * 256, NTOK, 768, 256, 2,
            nullptr, qbuf, kbuf, vtbf,
            bq + l * 256, bk + l * 256, bv + l * 256, 0);
        attn_mfma<<<dim3(32, NHD, BATCH), 256, 0, stream>>>(
            qbuf, kbuf, vtbf, kerple_p + l * NHD, kerple_a + l * NHD, o_bf);
        gemm64<<<dim3(128, 4), 256, 0, stream>>>(
            o_bf, WoT + (size_t)l * D2, NTOK, 256, 256, 5,
            nullptr, tmpb, bo + l * 256, nullptr, nullptr, nullptr, nullptr, nullptr);
        ln_kernel<<<NTOK, 256, 0, stream>>>(x, tmpb, ln1_g + l * 256, ln1_b + l * 256, xb);
        gemm_bf16_128<<<dim3(64, 8), 256, 0, stream>>>(
            xb, W1T + (size_t)l * 4 * D2, NTOK, 1024, 256, 1,
            nullptr, h_bf, nullptr, nullptr, ffn_b1 + l * 1024, nullptr, nullptr, 0);
        gemm64<<<dim3(128, 4), 256, 0, stream>>>(
            h_bf, W2T + (size_t)l * 4 * D2, NTOK, 256, 1024, 5,
            nullptr, tmpb, ffn_b2 + l * 256, nullptr, nullptr, nullptr, nullptr, nullptr);
        ln_kernel<<<NTOK, 256, 0, stream>>>(x, tmpb, ln2_g + l * 256, ln2_b + l * 256, xb);
    }

    // ---- output projection (N=2048 padded, guard to 2000, plain fp32 out) ----
    gemm_bf16_128<<<dim3(64, 16), 256, 0, stream>>>(
        xb, outWt, NTOK, 2048, 256, 3,
        out, nullptr, nullptr, nullptr, out_b, nullptr, nullptr, NSKC);
}

// Round 8
// 414.393 us; speedup vs baseline: 1.1793x; 1.0871x over previous
//
#include <hip/hip_runtime.h>
#include <math.h>

// B=4, S=2048, F=8, D=256, H=8, L=2, FF=1024, NSK=2000
#define SEQ   2048
#define BATCH 4
#define NTOK  8192
#define DM    256
#define NHD   8
#define DHD   32
#define DFF   1024
#define NSKC  2000

typedef __attribute__((ext_vector_type(8))) short short8;
typedef __attribute__((ext_vector_type(4))) float f32x4;
typedef unsigned short ushort_t;

// 1/sqrt(32) * log2(e): folded into Q so scores come out in exp2 domain.
#define QPRE ((float)(0.17677669529663687 * 1.4426950408889634))

// pair-interleave permutation within each 32-element block
#define SPERM(i) (((i) & ~31) | (((i) & 15) << 1) | (((i) >> 4) & 1))

__device__ __forceinline__ ushort_t f2bf(float x) {
    union { float f; unsigned u; } c; c.f = x;
    unsigned r = c.u + 0x7FFFu + ((c.u >> 16) & 1u);
    return (ushort_t)(r >> 16);
}

#if __has_builtin(__builtin_amdgcn_cvt_pk_bf16_f32)
typedef __attribute__((ext_vector_type(2))) __bf16 bf16x2_t;
__device__ __forceinline__ unsigned pack_bf16(float a, float b) {
    bf16x2_t r = __builtin_amdgcn_cvt_pk_bf16_f32(a, b);
    union { bf16x2_t v; unsigned u; } c; c.v = r;
    return c.u;
}
#else
__device__ __forceinline__ unsigned pack_bf16(float a, float b) {
    return (unsigned)f2bf(a) | ((unsigned)f2bf(b) << 16);
}
#endif

__device__ __forceinline__ float bf2f(ushort_t x) {
    union { unsigned u; float f; } c; c.u = ((unsigned)x) << 16;
    return c.f;
}

// ---------------------------------------------------------------------------
// Weight conversion, exact tile grid: dst[n][kperm(k)] = bf16(src[k][n]).
// ---------------------------------------------------------------------------
struct ConvSeg { const float* src; ushort_t* dst; int K; int N; int ntx; int base; int kperm; };
struct ConvArgs { ConvSeg s[14]; };

__global__ __launch_bounds__(256) void convert_kernel(ConvArgs args) {
    int bid = blockIdx.x;
    int si = 0;
#pragma unroll
    for (int i = 1; i < 14; i++) if (bid >= args.s[i].base) si = i;
    ConvSeg sg = args.s[si];
    int local = bid - sg.base;
    int ty = local / sg.ntx;
    int tx = local - ty * sg.ntx;
    int n0 = tx * 32, k0 = ty * 32;
    __shared__ float T[32][33];
    int tid = threadIdx.x;
    int tn = tid & 31, tk4 = tid >> 5;
#pragma unroll
    for (int i = 0; i < 4; i++) {
        int kl = tk4 + i * 8;
        float v = 0.0f;
        if (n0 + tn < sg.N) v = sg.src[(size_t)(k0 + kl) * sg.N + n0 + tn];
        T[kl][tn] = v;
    }
    __syncthreads();
    int tk = tid & 31, tn4 = tid >> 5;
    int tks = sg.kperm ? (((tk & 15) << 1) | ((tk >> 4) & 1)) : tk;
#pragma unroll
    for (int i = 0; i < 4; i++) {
        int nl = tn4 + i * 8;
        sg.dst[(size_t)(n0 + nl) * sg.K + k0 + tks] = f2bf(T[tk][nl]);
    }
}

// ---------------------------------------------------------------------------
// concat row [inter_e(256) | pat_e(64) | feat_e(64)] -> bf16 (plain layout)
// ---------------------------------------------------------------------------
__global__ __launch_bounds__(384) void concat_kernel(
    const int* __restrict__ interactions, const int* __restrict__ patterns,
    const float* __restrict__ ff, const float* __restrict__ inter_emb,
    const float* __restrict__ pattern_emb, const float* __restrict__ feat_W,
    const float* __restrict__ feat_b, ushort_t* __restrict__ out)
{
    int tok = blockIdx.x;
    int j = threadIdx.x;
    float v;
    if (j < 256) {
        v = inter_emb[(size_t)interactions[tok] * 256 + j];
    } else if (j < 320) {
        v = pattern_emb[patterns[tok] * 64 + (j - 256)];
    } else {
        int c = j - 320;
        float acc = feat_b[c];
#pragma unroll
        for (int f = 0; f < 8; f++) acc += ff[tok * 8 + f] * feat_W[f * 64 + c];
        v = acc;
    }
    out[(size_t)tok * 384 + j] = f2bf(v);
}

// ---------------------------------------------------------------------------
// LayerNorm(x + r) in place. r, xb pair-interleaved bf16; x fp32 plain.
// ---------------------------------------------------------------------------
__global__ __launch_bounds__(256) void ln_kernel(
    float* __restrict__ x, const ushort_t* __restrict__ r,
    const float* __restrict__ g, const float* __restrict__ b,
    ushort_t* __restrict__ xb)
{
    int tok = blockIdx.x;
    int d = threadIdx.x;
    int ds = SPERM(d);
    size_t row = (size_t)tok * DM;
    float v = x[row + d] + bf2f(r[row + ds]);
    float s1 = v, s2 = v * v;
#pragma unroll
    for (int off = 32; off > 0; off >>= 1) {
        s1 += __shfl_down(s1, off, 64);
        s2 += __shfl_down(s2, off, 64);
    }
    __shared__ float red1[4], red2[4];
    int wid = d >> 6, lane = d & 63;
    if (lane == 0) { red1[wid] = s1; red2[wid] = s2; }
    __syncthreads();
    s1 = red1[0] + red1[1] + red1[2] + red1[3];
    s2 = red2[0] + red2[1] + red2[2] + red2[3];
    float mean = s1 * (1.0f / 256.0f);
    float var = s2 * (1.0f / 256.0f) - mean * mean;
    float inv = rsqrtf(var + 1e-6f);
    float nv = g[d] * (v - mean) * inv + b[d];
    x[row + d] = nv;
    xb[row + ds] = f2bf(nv);
}

// ---------------------------------------------------------------------------
// gemm64: BM=64 BN=64 BK=32, double-buffered LDS (1 barrier/iter).
// 4 waves, each 16x64, 4 mfma/iter. blockIdx.x = m-tile (XCD swizzle).
// mode 4: in-proj epilogue -> x fp32 plain + xb packed
// mode 5: packed bf16 out + bias
// ---------------------------------------------------------------------------
__global__ __launch_bounds__(256) void gemm64(
    const ushort_t* __restrict__ A, const ushort_t* __restrict__ Bt,
    int M, int N, int K, int mode,
    float* __restrict__ Cf, ushort_t* __restrict__ Cb,
    const float* __restrict__ b0,
    const float* __restrict__ ffg, const float* __restrict__ tW,
    const float* __restrict__ tb, const float* __restrict__ pW,
    const float* __restrict__ pb)
{
    __shared__ ushort_t As[2][64][40];
    __shared__ ushort_t Bs[2][64][40];
    int m0 = blockIdx.x * 64, n0 = blockIdx.y * 64;
    int tid = threadIdx.x;
    int wv = tid >> 6, lane = tid & 63;
    int quad = lane >> 4, l16 = lane & 15;
    int srow = tid >> 2, sc = (tid & 3) << 3;

    f32x4 acc[4];
#pragma unroll
    for (int j = 0; j < 4; j++) acc[j] = (f32x4){0.f, 0.f, 0.f, 0.f};

    uint4 pa = *(const uint4*)&A[(size_t)(m0 + srow) * K + sc];
    uint4 pbv = *(const uint4*)&Bt[(size_t)(n0 + srow) * K + sc];
    *(uint4*)&As[0][srow][sc] = pa;
    *(uint4*)&Bs[0][srow][sc] = pbv;

    int mrow = wv * 16;
    for (int k0 = 0; k0 < K; k0 += 32) {
        int cur = (k0 >> 5) & 1;
        __syncthreads();
        bool more = (k0 + 32 < K);
        if (more) {
            pa = *(const uint4*)&A[(size_t)(m0 + srow) * K + k0 + 32 + sc];
            pbv = *(const uint4*)&Bt[(size_t)(n0 + srow) * K + k0 + 32 + sc];
        }
        short8 af = *(const short8*)&As[cur][mrow + l16][quad * 8];
        short8 bf0 = *(const short8*)&Bs[cur][l16][quad * 8];
        short8 bf1 = *(const short8*)&Bs[cur][16 + l16][quad * 8];
        short8 bf2 = *(const short8*)&Bs[cur][32 + l16][quad * 8];
        short8 bf3 = *(const short8*)&Bs[cur][48 + l16][quad * 8];
        acc[0] = __builtin_amdgcn_mfma_f32_16x16x32_bf16(af, bf0, acc[0], 0, 0, 0);
        acc[1] = __builtin_amdgcn_mfma_f32_16x16x32_bf16(af, bf1, acc[1], 0, 0, 0);
        acc[2] = __builtin_amdgcn_mfma_f32_16x16x32_bf16(af, bf2, acc[2], 0, 0, 0);
        acc[3] = __builtin_amdgcn_mfma_f32_16x16x32_bf16(af, bf3, acc[3], 0, 0, 0);
        if (more) {
            *(uint4*)&As[cur ^ 1][srow][sc] = pa;
            *(uint4*)&Bs[cur ^ 1][srow][sc] = pbv;
        }
    }

#pragma unroll
    for (int r = 0; r < 4; r++) {
        int m = m0 + mrow + quad * 4 + r;
        if (mode == 4) {
            int s = m & (SEQ - 1);
            float el = ffg[m * 8];
            float pos = (float)s * (1.0f / (float)SEQ);
#pragma unroll
            for (int nt = 0; nt < 4; nt += 2) {
                int nlo = n0 + nt * 16 + l16;
                int nhi = nlo + 16;
                float v0 = acc[nt][r] + b0[nlo] + tanhf(el * tW[nlo] + tb[nlo]) + pos * pW[nlo] + pb[nlo];
                float v1 = acc[nt + 1][r] + b0[nhi] + tanhf(el * tW[nhi] + tb[nhi]) + pos * pW[nhi] + pb[nhi];
                Cf[(size_t)m * N + nlo] = v0;
                Cf[(size_t)m * N + nhi] = v1;
                *(unsigned*)&Cb[(size_t)m * N + n0 + nt * 16 + 2 * l16] = pack_bf16(v0, v1);
            }
        } else {
#pragma unroll
            for (int nt = 0; nt < 4; nt += 2) {
                int nlo = n0 + nt * 16 + l16;
                float v0 = acc[nt][r] + b0[nlo];
                float v1 = acc[nt + 1][r] + b0[nlo + 16];
                *(unsigned*)&Cb[(size_t)m * N + n0 + nt * 16 + 2 * l16] = pack_bf16(v0, v1);
            }
        }
    }
}

// ---------------------------------------------------------------------------
// gemm_db: BM=128 BN=64 BK=32, double-buffered (1 barrier/iter).
// 4 waves, each 32x64, 8 mfma/iter. Grids: QKV (64,12), FFN1 (64,16).
// mode 1: gelu -> packed bf16
// mode 2: QKV epilogue (q pre-scaled + k packed-pair (B,H,S,DH); v -> V^T
//         (B,H,DH,S) pair-interleaved s-columns)
// ---------------------------------------------------------------------------
__global__ __launch_bounds__(256) void gemm_db(
    const ushort_t* __restrict__ A, const ushort_t* __restrict__ Bt,
    int M, int N, int K, int mode,
    ushort_t* __restrict__ Cb, ushort_t* __restrict__ Ck, ushort_t* __restrict__ Cv,
    const float* __restrict__ b0, const float* __restrict__ b1,
    const float* __restrict__ b2)
{
    __shared__ ushort_t As[2][128][40];
    __shared__ ushort_t Bs[2][64][40];
    int m0 = blockIdx.x * 128, n0 = blockIdx.y * 64;
    int tid = threadIdx.x;
    int wv = tid >> 6, lane = tid & 63;
    int quad = lane >> 4, l16 = lane & 15;
    int srow = tid >> 2, sc = (tid & 3) << 3;

    f32x4 acc[2][4];
#pragma unroll
    for (int i = 0; i < 2; i++)
#pragma unroll
        for (int j = 0; j < 4; j++) acc[i][j] = (f32x4){0.f, 0.f, 0.f, 0.f};

    uint4 pa0 = *(const uint4*)&A[(size_t)(m0 + srow) * K + sc];
    uint4 pa1 = *(const uint4*)&A[(size_t)(m0 + 64 + srow) * K + sc];
    uint4 pbb = *(const uint4*)&Bt[(size_t)(n0 + srow) * K + sc];
    *(uint4*)&As[0][srow][sc] = pa0;
    *(uint4*)&As[0][64 + srow][sc] = pa1;
    *(uint4*)&Bs[0][srow][sc] = pbb;

    int msub = wv * 32;
    for (int k0 = 0; k0 < K; k0 += 32) {
        int cur = (k0 >> 5) & 1;
        __syncthreads();
        bool more = (k0 + 32 < K);
        if (more) {
            pa0 = *(const uint4*)&A[(size_t)(m0 + srow) * K + k0 + 32 + sc];
            pa1 = *(const uint4*)&A[(size_t)(m0 + 64 + srow) * K + k0 + 32 + sc];
            pbb = *(const uint4*)&Bt[(size_t)(n0 + srow) * K + k0 + 32 + sc];
        }
        short8 af0 = *(const short8*)&As[cur][msub + l16][quad * 8];
        short8 af1 = *(const short8*)&As[cur][msub + 16 + l16][quad * 8];
        short8 bf0 = *(const short8*)&Bs[cur][l16][quad * 8];
        short8 bf1 = *(const short8*)&Bs[cur][16 + l16][quad * 8];
        short8 bf2 = *(const short8*)&Bs[cur][32 + l16][quad * 8];
        short8 bf3 = *(const short8*)&Bs[cur][48 + l16][quad * 8];
        acc[0][0] = __builtin_amdgcn_mfma_f32_16x16x32_bf16(af0, bf0, acc[0][0], 0, 0, 0);
        acc[0][1] = __builtin_amdgcn_mfma_f32_16x16x32_bf16(af0, bf1, acc[0][1], 0, 0, 0);
        acc[0][2] = __builtin_amdgcn_mfma_f32_16x16x32_bf16(af0, bf2, acc[0][2], 0, 0, 0);
        acc[0][3] = __builtin_amdgcn_mfma_f32_16x16x32_bf16(af0, bf3, acc[0][3], 0, 0, 0);
        acc[1][0] = __builtin_amdgcn_mfma_f32_16x16x32_bf16(af1, bf0, acc[1][0], 0, 0, 0);
        acc[1][1] = __builtin_amdgcn_mfma_f32_16x16x32_bf16(af1, bf1, acc[1][1], 0, 0, 0);
        acc[1][2] = __builtin_amdgcn_mfma_f32_16x16x32_bf16(af1, bf2, acc[1][2], 0, 0, 0);
        acc[1][3] = __builtin_amdgcn_mfma_f32_16x16x32_bf16(af1, bf3, acc[1][3], 0, 0, 0);
        if (more) {
            *(uint4*)&As[cur ^ 1][srow][sc] = pa0;
            *(uint4*)&As[cur ^ 1][64 + srow][sc] = pa1;
            *(uint4*)&Bs[cur ^ 1][srow][sc] = pbb;
        }
    }

#pragma unroll
    for (int mt = 0; mt < 2; mt++) {
#pragma unroll
        for (int nt = 0; nt < 4; nt += 2) {
            int nlo = n0 + nt * 16 + l16;
#pragma unroll
            for (int r = 0; r < 4; r++) {
                int m = m0 + msub + mt * 16 + quad * 4 + r;
                float vlo = acc[mt][nt][r];
                float vhi = acc[mt][nt + 1][r];
                if (mode == 1) {
                    float t0 = vlo + b0[nlo];
                    float t1 = vhi + b0[nlo + 16];
                    t0 = 0.5f * t0 * (1.0f + erff(t0 * 0.70710678118654752f));
                    t1 = 0.5f * t1 * (1.0f + erff(t1 * 0.70710678118654752f));
                    *(unsigned*)&Cb[(size_t)m * N + n0 + nt * 16 + 2 * l16] = pack_bf16(t0, t1);
                } else {
                    int which = nlo >> 8, idx = nlo & 255;
                    int hh = idx >> 5;          // d == l16, partner d+16 same head
                    int s = m & (SEQ - 1), b = m >> 11;
                    if (which == 0) {
                        float q0 = (vlo + b0[idx]) * QPRE;
                        float q1 = (vhi + b0[idx + 16]) * QPRE;
                        *(unsigned*)&Cb[(((size_t)(b * NHD + hh)) * SEQ + s) * DHD + 2 * l16] = pack_bf16(q0, q1);
                    } else if (which == 1) {
                        float k0v = vlo + b1[idx];
                        float k1v = vhi + b1[idx + 16];
                        *(unsigned*)&Ck[(((size_t)(b * NHD + hh)) * SEQ + s) * DHD + 2 * l16] = pack_bf16(k0v, k1v);
                    } else {
                        int sp = (s & ~31) | (((s & 15) << 1) | ((s >> 4) & 1));
                        Cv[(((size_t)(b * NHD + hh)) * DHD + l16) * SEQ + sp] = f2bf(vlo + b2[idx]);
                        Cv[(((size_t)(b * NHD + hh)) * DHD + l16 + 16) * SEQ + sp] = f2bf(vhi + b2[idx + 16]);
                    }
                }
            }
        }
    }
}

// ---------------------------------------------------------------------------
// gemm_out: BM=128 BN=128 BK=32, double-buffered. fp32 + bias, n < Nreal.
// LDS 40 KB -> exactly 4 blocks/CU.
// ---------------------------------------------------------------------------
__global__ __launch_bounds__(256) void gemm_out(
    const ushort_t* __restrict__ A, const ushort_t* __restrict__ Bt,
    int M, int N, int K,
    float* __restrict__ Cf, const float* __restrict__ b0, int Nreal)
{
    __shared__ ushort_t As[2][128][40];
    __shared__ ushort_t Bs[2][128][40];
    int m0 = blockIdx.x * 128, n0 = blockIdx.y * 128;
    int tid = threadIdx.x;
    int wv = tid >> 6, lane = tid & 63;
    int quad = lane >> 4, l16 = lane & 15;
    int wm = (wv >> 1) * 64, wn = (wv & 1) * 64;
    int srow = tid >> 1, sc = (tid & 1) << 4;

    f32x4 acc[4][4];
#pragma unroll
    for (int i = 0; i < 4; i++)
#pragma unroll
        for (int j = 0; j < 4; j++) acc[i][j] = (f32x4){0.f, 0.f, 0.f, 0.f};

    uint4 pa0 = *(const uint4*)&A[(size_t)(m0 + srow) * K + sc];
    uint4 pa1 = *(const uint4*)&A[(size_t)(m0 + srow) * K + sc + 8];
    uint4 pb0 = *(const uint4*)&Bt[(size_t)(n0 + srow) * K + sc];
    uint4 pb1 = *(const uint4*)&Bt[(size_t)(n0 + srow) * K + sc + 8];
    *(uint4*)&As[0][srow][sc] = pa0;
    *(uint4*)&As[0][srow][sc + 8] = pa1;
    *(uint4*)&Bs[0][srow][sc] = pb0;
    *(uint4*)&Bs[0][srow][sc + 8] = pb1;

    for (int k0 = 0; k0 < K; k0 += 32) {
        int cur = (k0 >> 5) & 1;
        __syncthreads();
        bool more = (k0 + 32 < K);
        if (more) {
            pa0 = *(const uint4*)&A[(size_t)(m0 + srow) * K + k0 + 32 + sc];
            pa1 = *(const uint4*)&A[(size_t)(m0 + srow) * K + k0 + 32 + sc + 8];
            pb0 = *(const uint4*)&Bt[(size_t)(n0 + srow) * K + k0 + 32 + sc];
            pb1 = *(const uint4*)&Bt[(size_t)(n0 + srow) * K + k0 + 32 + sc + 8];
        }
        short8 af[4], bf[4];
#pragma unroll
        for (int i = 0; i < 4; i++) {
            af[i] = *(const short8*)&As[cur][wm + i * 16 + l16][quad * 8];
            bf[i] = *(const short8*)&Bs[cur][wn + i * 16 + l16][quad * 8];
        }
#pragma unroll
        for (int i = 0; i < 4; i++)
#pragma unroll
            for (int j = 0; j < 4; j++)
                acc[i][j] = __builtin_amdgcn_mfma_f32_16x16x32_bf16(af[i], bf[j], acc[i][j], 0, 0, 0);
        if (more) {
            *(uint4*)&As[cur ^ 1][srow][sc] = pa0;
            *(uint4*)&As[cur ^ 1][srow][sc + 8] = pa1;
            *(uint4*)&Bs[cur ^ 1][srow][sc] = pb0;
            *(uint4*)&Bs[cur ^ 1][srow][sc + 8] = pb1;
        }
    }

#pragma unroll
    for (int i = 0; i < 4; i++) {
#pragma unroll
        for (int j = 0; j < 4; j++) {
            int n = n0 + wn + j * 16 + l16;
            if (n < Nreal) {
#pragma unroll
                for (int r = 0; r < 4; r++) {
                    int m = m0 + wm + i * 16 + quad * 4 + r;
                    Cf[(size_t)m * Nreal + n] = acc[i][j][r] + b0[n];
                }
            }
        }
    }
}

// ---------------------------------------------------------------------------
// MFMA flash attention (unchanged from R7).
// ---------------------------------------------------------------------------
__global__ __launch_bounds__(256) void attn_mfma(
    const ushort_t* __restrict__ qb, const ushort_t* __restrict__ kb,
    const ushort_t* __restrict__ vtb, const float* __restrict__ kp,
    const float* __restrict__ ka, ushort_t* __restrict__ ob)
{
    int h = blockIdx.y, b = blockIdx.z;
    int tid = threadIdx.x, wv = tid >> 6, lane = tid & 63;
    int quad = lane >> 4, l16 = lane & 15;
    int pair = wv >> 1, parity = wv & 1;

    __shared__ float tabs[2112];
    __shared__ ushort_t P2[4][2][16 * 40];
    __shared__ float Cmb[2][64][28];

    float p = log1pf(__expf(kp[h]));
    float a = log1pf(__expf(ka[h]));
    for (int i = tid; i < 2112; i += 256) {
        float w = 0.0f;
        if (i >= 64) w = exp2f(-p * __log2f(fmaf(a, (float)(i - 64), 1.0f)));
        tabs[i] = w;
    }
    __syncthreads();

    int bh = b * NHD + h;
    const ushort_t* Qh = qb + (size_t)bh * SEQ * DHD;
    const ushort_t* Kh = kb + (size_t)bh * SEQ * DHD;
    const ushort_t* Vh = vtb + (size_t)bh * DHD * SEQ;

    int pj = blockIdx.x * 2 + pair;
    int tlo = pj, thi = 127 - pj;
    int qlo0 = tlo * 16, qhi0 = thi * 16;

    short8 qfl = *(const short8*)&Qh[(qlo0 + l16) * DHD + quad * 8];
    short8 qfh = *(const short8*)&Qh[(qhi0 + l16) * DHD + quad * 8];
    f32x4 ol0 = (f32x4){0.f,0.f,0.f,0.f}, ol1 = (f32x4){0.f,0.f,0.f,0.f};
    f32x4 oh0 = (f32x4){0.f,0.f,0.f,0.f}, oh1 = (f32x4){0.f,0.f,0.f,0.f};
    float lsl[4] = {0.f,0.f,0.f,0.f}, lsh[4] = {0.f,0.f,0.f,0.f};
    ushort_t* Pl = &P2[wv][0][0];
    ushort_t* Ph = &P2[wv][1][0];

    int nch_hi = (thi + 2) >> 1;
    int nch_lo = (tlo + 2) >> 1;
    int qsrh = qhi0 + quad * 4;
    int qsrl = qlo0 + quad * 4;

    for (int ch = parity; ch < nch_hi; ch += 2) {
        int k0 = ch * 32;
        short8 kf0 = *(const short8*)&Kh[(k0 + l16) * DHD + quad * 8];
        short8 kf1 = *(const short8*)&Kh[(k0 + 16 + l16) * DHD + quad * 8];
        short8 vf0 = *(const short8*)&Vh[l16 * SEQ + k0 + quad * 8];
        short8 vf1 = *(const short8*)&Vh[(16 + l16) * SEQ + k0 + quad * 8];
        f32x4 z = (f32x4){0.f,0.f,0.f,0.f};

        f32x4 s0 = __builtin_amdgcn_mfma_f32_16x16x32_bf16(qfh, kf0, z, 0, 0, 0);
        f32x4 s1 = __builtin_amdgcn_mfma_f32_16x16x32_bf16(qfh, kf1, z, 0, 0, 0);
        {
            const float* tp = &tabs[qsrh - k0 - l16 + 48];
#pragma unroll
            for (int r = 0; r < 4; r++) {
                float e0 = exp2f(s0[r]) * tp[16 + r];
                float e1 = exp2f(s1[r]) * tp[r];
                lsh[r] += e0 + e1;
                *(unsigned*)&Ph[(quad * 4 + r) * 40 + l16 * 2] = pack_bf16(e0, e1);
            }
        }
        bool do_lo = (ch < nch_lo);
        if (do_lo) {
            f32x4 t0 = __builtin_amdgcn_mfma_f32_16x16x32_bf16(qfl, kf0, z, 0, 0, 0);
            f32x4 t1 = __builtin_amdgcn_mfma_f32_16x16x32_bf16(qfl, kf1, z, 0, 0, 0);
            const float* tq = &tabs[qsrl - k0 - l16 + 48];
#pragma unroll
            for (int r = 0; r < 4; r++) {
                float e0 = exp2f(t0[r]) * tq[16 + r];
                float e1 = exp2f(t1[r]) * tq[r];
                lsl[r] += e0 + e1;
                *(unsigned*)&Pl[(quad * 4 + r) * 40 + l16 * 2] = pack_bf16(e0, e1);
            }
        }

        __builtin_amdgcn_wave_barrier();
        short8 pfh = *(const short8*)&Ph[l16 * 40 + quad * 8];
        oh0 = __builtin_amdgcn_mfma_f32_16x16x32_bf16(pfh, vf0, oh0, 0, 0, 0);
        oh1 = __builtin_amdgcn_mfma_f32_16x16x32_bf16(pfh, vf1, oh1, 0, 0, 0);
        if (do_lo) {
            short8 pfl = *(const short8*)&Pl[l16 * 40 + quad * 8];
            ol0 = __builtin_amdgcn_mfma_f32_16x16x32_bf16(pfl, vf0, ol0, 0, 0, 0);
            ol1 = __builtin_amdgcn_mfma_f32_16x16x32_bf16(pfl, vf1, ol1, 0, 0, 0);
        }
    }

    if (parity == 1) {
        float* cp = &Cmb[pair][lane][0];
        *(float4*)&cp[0]  = (float4){oh0[0], oh0[1], oh0[2], oh0[3]};
        *(float4*)&cp[4]  = (float4){oh1[0], oh1[1], oh1[2], oh1[3]};
        *(float4*)&cp[8]  = (float4){ol0[0], ol0[1], ol0[2], ol0[3]};
        *(float4*)&cp[12] = (float4){ol1[0], ol1[1], ol1[2], ol1[3]};
        *(float4*)&cp[16] = (float4){lsh[0], lsh[1], lsh[2], lsh[3]};
        *(float4*)&cp[20] = (float4){lsl[0], lsl[1], lsl[2], lsl[3]};
    }
    __syncthreads();
    if (parity == 0) {
        const float* cp = &Cmb[pair][lane][0];
#pragma unroll
        for (int i = 0; i < 4; i++) {
            oh0[i] += cp[i];      oh1[i] += cp[4 + i];
            ol0[i] += cp[8 + i];  ol1[i] += cp[12 + i];
            lsh[i] += cp[16 + i]; lsl[i] += cp[20 + i];
        }
#pragma unroll
        for (int r = 0; r < 4; r++) {
#pragma unroll
            for (int off = 1; off < 16; off <<= 1) {
                lsh[r] += __shfl_xor(lsh[r], off, 16);
                lsl[r] += __shfl_xor(lsl[r], off, 16);
            }
        }
#pragma unroll
        for (int r = 0; r < 4; r++) {
            float rh = 1.0f / lsh[r];
            float rl = 1.0f / lsl[r];
            size_t bh_ = ((size_t)(b * SEQ + qsrh + r)) * DM + h * DHD;
            size_t bl_ = ((size_t)(b * SEQ + qsrl + r)) * DM + h * DHD;
            *(unsigned*)&ob[bh_ + 2 * l16] = pack_bf16(oh0[r] * rh, oh1[r] * rh);
            *(unsigned*)&ob[bl_ + 2 * l16] = pack_bf16(ol0[r] * rl, ol1[r] * rl);
        }
    }
}

// ---------------------------------------------------------------------------
extern "C" void kernel_launch(void* const* d_in, const int* in_sizes, int n_in,
                              void* d_out, int out_size, void* d_ws, size_t ws_size,
                              hipStream_t stream) {
    const int*   interactions = (const int*)d_in[0];
    const int*   patterns     = (const int*)d_in[1];
    const float* ff           = (const float*)d_in[2];
    const float* inter_emb    = (const float*)d_in[3];
    const float* pattern_emb  = (const float*)d_in[4];
    const float* feat_W       = (const float*)d_in[5];
    const float* feat_b       = (const float*)d_in[6];
    const float* in_W         = (const float*)d_in[7];
    const float* in_b         = (const float*)d_in[8];
    const float* time_W       = (const float*)d_in[9];
    const float* time_b       = (const float*)d_in[10];
    const float* pos_W        = (const float*)d_in[11];
    const float* pos_b        = (const float*)d_in[12];
    const float* Wq           = (const float*)d_in[13];
    const float* bq           = (const float*)d_in[14];
    const float* Wk           = (const float*)d_in[15];
    const float* bk           = (const float*)d_in[16];
    const float* Wv           = (const float*)d_in[17];
    const float* bv           = (const float*)d_in[18];
    const float* Wo           = (const float*)d_in[19];
    const float* bo           = (const float*)d_in[20];
    const float* kerple_p     = (const float*)d_in[21];
    const float* kerple_a     = (const float*)d_in[22];
    const float* ln1_g        = (const float*)d_in[23];
    const float* ln1_b        = (const float*)d_in[24];
    const float* ln2_g        = (const float*)d_in[25];
    const float* ln2_b        = (const float*)d_in[26];
    const float* ffn_W1       = (const float*)d_in[27];
    const float* ffn_b1       = (const float*)d_in[28];
    const float* ffn_W2       = (const float*)d_in[29];
    const float* ffn_b2       = (const float*)d_in[30];
    const float* out_W        = (const float*)d_in[31];
    const float* out_b        = (const float*)d_in[32];
    float* out = (float*)d_out;

    // ---- workspace layout (bytes) ----
    char* wsb = (char*)d_ws;
    const size_t MB = 1024 * 1024;
    float*    x    = (float*)(wsb + 0);          //  8 MB fp32 activations (plain)
    ushort_t* tmpb = (ushort_t*)(wsb + 8  * MB); //  4 MB bf16 residual (perm)
    ushort_t* xb   = (ushort_t*)(wsb + 16 * MB); //  4 MB bf16 x copy (perm)
    ushort_t* qbuf = (ushort_t*)(wsb + 20 * MB); //  4 MB Q (B,H,S,DH) d-perm, pre-scaled
    ushort_t* kbuf = (ushort_t*)(wsb + 24 * MB); //  4 MB K (B,H,S,DH) d-perm
    ushort_t* vtbf = (ushort_t*)(wsb + 28 * MB); //  4 MB V^T (B,H,DH,S) s-perm
    ushort_t* shrd = (ushort_t*)(wsb + 32 * MB); // 16 MB: cbuf / o_bf / h_bf
    ushort_t* cbuf = shrd;
    ushort_t* o_bf = shrd;
    ushort_t* h_bf = shrd;
    char* wp = wsb + 48 * MB;
    ushort_t* inWt  = (ushort_t*)wp;  wp += 256  * 384 * 2;
    ushort_t* qkvWt = (ushort_t*)wp;  wp += 2 * 768 * 256 * 2;
    ushort_t* WoT   = (ushort_t*)wp;  wp += 2 * 256 * 256 * 2;
    ushort_t* W1T   = (ushort_t*)wp;  wp += 2 * 1024 * 256 * 2;
    ushort_t* W2T   = (ushort_t*)wp;  wp += 2 * 256 * 1024 * 2;
    ushort_t* outWt = (ushort_t*)wp;  wp += 2048 * 256 * 2;

    // ---- weight conversion ----
    ConvArgs ca;
    int D2 = 256 * 256;
    int base = 0, ib = 0;
    auto addseg = [&](const float* src, ushort_t* dst, int K, int N, int Npad, int kp) {
        ca.s[ib].src = src; ca.s[ib].dst = dst; ca.s[ib].K = K; ca.s[ib].N = N;
        ca.s[ib].ntx = Npad / 32; ca.s[ib].base = base; ca.s[ib].kperm = kp;
        base += (Npad / 32) * (K / 32); ib++;
    };
    addseg(in_W,            inWt,           384,  256,  256,  0);
    addseg(Wq,              qkvWt,          256,  256,  256,  1);
    addseg(Wk,              qkvWt + 1 * D2, 256,  256,  256,  1);
    addseg(Wv,              qkvWt + 2 * D2, 256,  256,  256,  1);
    addseg(Wq + D2,         qkvWt + 3 * D2, 256,  256,  256,  1);
    addseg(Wk + D2,         qkvWt + 4 * D2, 256,  256,  256,  1);
    addseg(Wv + D2,         qkvWt + 5 * D2, 256,  256,  256,  1);
    addseg(Wo,              WoT,            256,  256,  256,  1);
    addseg(Wo + D2,         WoT + D2,       256,  256,  256,  1);
    addseg(ffn_W1,          W1T,            256,  1024, 1024, 1);
    addseg(ffn_W1 + 4 * D2, W1T + 4 * D2,   256,  1024, 1024, 1);
    addseg(ffn_W2,          W2T,            1024, 256,  256,  1);
    addseg(ffn_W2 + 4 * D2, W2T + 4 * D2,   1024, 256,  256,  1);
    addseg(out_W,           outWt,          256,  2000, 2048, 1);
    convert_kernel<<<base, 256, 0, stream>>>(ca);

    // ---- input projection (+ fused time/pos encodings) ----
    concat_kernel<<<NTOK, 384, 0, stream>>>(interactions, patterns, ff,
                                            inter_emb, pattern_emb, feat_W, feat_b, cbuf);
    gemm64<<<dim3(128, 4), 256, 0, stream>>>(cbuf, inWt, NTOK, 256, 384, 4,
                                             x, xb, in_b, ff, time_W, time_b, pos_W, pos_b);

    for (int l = 0; l < 2; l++) {
        gemm_db<<<dim3(64, 12), 256, 0, stream>>>(
            xb, qkvWt + (size_t)l * 768 * 256, NTOK, 768, 256, 2,
            qbuf, kbuf, vtbf, bq + l * 256, bk + l * 256, bv + l * 256);
        attn_mfma<<<dim3(32, NHD, BATCH), 256, 0, stream>>>(
            qbuf, kbuf, vtbf, kerple_p + l * NHD, kerple_a + l * NHD, o_bf);
        gemm64<<<dim3(128, 4), 256, 0, stream>>>(
            o_bf, WoT + (size_t)l * D2, NTOK, 256, 256, 5,
            nullptr, tmpb, bo + l * 256, nullptr, nullptr, nullptr, nullptr, nullptr);
        ln_kernel<<<NTOK, 256, 0, stream>>>(x, tmpb, ln1_g + l * 256, ln1_b + l * 256, xb);
        gemm_db<<<dim3(64, 16), 256, 0, stream>>>(
            xb, W1T + (size_t)l * 4 * D2, NTOK, 1024, 256, 1,
            h_bf, nullptr, nullptr, ffn_b1 + l * 1024, nullptr, nullptr);
        gemm64<<<dim3(128, 4), 256, 0, stream>>>(
            h_bf, W2T + (size_t)l * 4 * D2, NTOK, 256, 1024, 5,
            nullptr, tmpb, ffn_b2 + l * 256, nullptr, nullptr, nullptr, nullptr, nullptr);
        ln_kernel<<<NTOK, 256, 0, stream>>>(x, tmpb, ln2_g + l * 256, ln2_b + l * 256, xb);
    }

    // ---- output projection (N=2048 padded, guard to 2000, plain fp32 out) ----
    gemm_out<<<dim3(64, 16), 256, 0, stream>>>(
        xb, outWt, NTOK, 2048, 256, out, out_b, NSKC);
}